// Round 1
// baseline (306.043 us; speedup 1.0000x reference)
//
#include <hip/hip_runtime.h>
#include <hip/hip_bf16.h>

typedef __attribute__((ext_vector_type(8))) short s16x8;
typedef __attribute__((ext_vector_type(4))) float f32x4;

#define TSEQ 4096
#define NBATCH 4

static __device__ __forceinline__ ushort f2bf(float f) {
    union { float f; unsigned u; } v; v.f = f;
    unsigned u = v.u;
    unsigned r = (u + 0x7fffu + ((u >> 16) & 1u)) >> 16;
    return (ushort)r;
}

// ---------------- K0: weight prep ----------------
// wt[192][1024] bf16: rows 0-63 = Wq^T (scaled by 1/32), 64-127 = Wk^T, 128-191 = Wv^T
__global__ __launch_bounds__(256) void prep_w(const float* __restrict__ Wk,
                                              const float* __restrict__ Wq,
                                              const float* __restrict__ Wv,
                                              ushort* __restrict__ wt) {
    __shared__ float tile[64][65];
    int bid = blockIdx.x;
    int mi = bid >> 4;               // 0=q, 1=k, 2=v
    int e0 = (bid & 15) << 6;
    const float* src = (mi == 0) ? Wq : (mi == 1) ? Wk : Wv;
    int n = threadIdx.x & 63;
    int quad = threadIdx.x >> 6;
#pragma unroll
    for (int r = 0; r < 16; ++r) {
        int el = r * 4 + quad;
        tile[el][n] = src[(size_t)(e0 + el) * 64 + n];
    }
    __syncthreads();
    float scale = (mi == 0) ? 0.03125f : 1.0f;   // fold E^-0.5 into q
    int ecol = threadIdx.x & 63;
#pragma unroll
    for (int r = 0; r < 16; ++r) {
        int nl = r * 4 + quad;
        wt[(size_t)(mi * 64 + nl) * 1024 + e0 + ecol] = f2bf(tile[ecol][nl] * scale);
    }
}

// ---------------- K1: QKV projection ----------------
// qb/kb: [B*T][64] bf16.  vt: [B][64][T] bf16 (transposed).
__global__ __launch_bounds__(64) void proj(const float* __restrict__ x,
                                           const ushort* __restrict__ wt,
                                           ushort* __restrict__ qb,
                                           ushort* __restrict__ kb,
                                           ushort* __restrict__ vt) {
    int lane = threadIdx.x;
    int l15 = lane & 15, g = lane >> 4;
    size_t m0 = (size_t)blockIdx.x * 16;

    f32x4 acc[12];
#pragma unroll
    for (int i = 0; i < 12; ++i) acc[i] = (f32x4){0.f, 0.f, 0.f, 0.f};

    const float* xrow = x + (m0 + l15) * 1024;
#pragma unroll 2
    for (int e0 = 0; e0 < 1024; e0 += 32) {
        int e = e0 + g * 8;
        f32x4 xa = *(const f32x4*)(xrow + e);
        f32x4 xb = *(const f32x4*)(xrow + e + 4);
        s16x8 a;
        a[0] = (short)f2bf(xa[0]); a[1] = (short)f2bf(xa[1]);
        a[2] = (short)f2bf(xa[2]); a[3] = (short)f2bf(xa[3]);
        a[4] = (short)f2bf(xb[0]); a[5] = (short)f2bf(xb[1]);
        a[6] = (short)f2bf(xb[2]); a[7] = (short)f2bf(xb[3]);
#pragma unroll
        for (int nf = 0; nf < 12; ++nf) {
            s16x8 b = *(const s16x8*)(wt + (size_t)(l15 + 16 * nf) * 1024 + e);
            acc[nf] = __builtin_amdgcn_mfma_f32_16x16x32_bf16(a, b, acc[nf], 0, 0, 0);
        }
    }

    // store q, k (C layout: col n = l15+16nf, row m = m0 + 4g + r)
#pragma unroll
    for (int nf = 0; nf < 4; ++nf) {
#pragma unroll
        for (int r = 0; r < 4; ++r) {
            qb[(m0 + 4 * g + r) * 64 + l15 + 16 * nf] = f2bf(acc[nf][r]);
            kb[(m0 + 4 * g + r) * 64 + l15 + 16 * nf] = f2bf(acc[4 + nf][r]);
        }
    }

    // v: transpose 16x64 tile through LDS, write vt[b][h][t] coalesced per-row
    __shared__ ushort vtile[16][72];
#pragma unroll
    for (int nf = 0; nf < 4; ++nf) {
#pragma unroll
        for (int r = 0; r < 4; ++r)
            vtile[4 * g + r][l15 + 16 * nf] = f2bf(acc[8 + nf][r]);
    }
    __syncthreads();
    unsigned pk[8];
#pragma unroll
    for (int i = 0; i < 8; ++i) {
        unsigned lo = vtile[2 * i][lane];
        unsigned hi = vtile[2 * i + 1][lane];
        pk[i] = lo | (hi << 16);
    }
    size_t b = m0 >> 12;
    size_t t0 = m0 & 4095;
    uint4* dst = (uint4*)(vt + (b * 64 + lane) * TSEQ + t0);
    dst[0] = make_uint4(pk[0], pk[1], pk[2], pk[3]);
    dst[1] = make_uint4(pk[4], pk[5], pk[6], pk[7]);
}

// ---------------- K2: causal flash attention ----------------
// 1 wave per block; each block: batch b, 16 q-rows. Swapped QK^T (S^T = K*Q),
// online softmax per-lane (lane owns q = l15), PV accumulates O^T.
__global__ __launch_bounds__(64) void attn(const ushort* __restrict__ qb,
                                           const ushort* __restrict__ kb,
                                           const ushort* __restrict__ vt,
                                           float* __restrict__ out) {
    __shared__ ushort pl[2][16][72];
    int lane = threadIdx.x;
    int l15 = lane & 15, g = lane >> 4;
    int bid = blockIdx.x;
    int b = bid & 3;
    int qt = 255 - (bid >> 2);       // heavy-first
    int q0 = qt << 4;
    int q = q0 + l15;

    // Q fragments (B operand: col q = l15, h-slots by g), hoisted
    const ushort* qbase = qb + ((size_t)b * TSEQ + q0 + l15) * 64;
    s16x8 qf0 = *(const s16x8*)(qbase + g * 8);
    s16x8 qf1 = *(const s16x8*)(qbase + 32 + g * 8);

    f32x4 o[4];
#pragma unroll
    for (int i = 0; i < 4; ++i) o[i] = (f32x4){0.f, 0.f, 0.f, 0.f};
    float m = -1e30f, lsum = 0.f;

    int nkv = (q0 + 16 + 63) >> 6;
    for (int t = 0; t < nkv; ++t) {
        int kbase = t << 6;
        const ushort* kt = kb + ((size_t)b * TSEQ + kbase) * 64;

        // QK^T: S^T frags st[kf]: col q = l15, row k_local = 4g + r
        f32x4 st[4];
#pragma unroll
        for (int kf = 0; kf < 4; ++kf) {
            s16x8 ka0 = *(const s16x8*)(kt + (kf * 16 + l15) * 64 + g * 8);
            s16x8 ka1 = *(const s16x8*)(kt + (kf * 16 + l15) * 64 + 32 + g * 8);
            f32x4 z = (f32x4){0.f, 0.f, 0.f, 0.f};
            z = __builtin_amdgcn_mfma_f32_16x16x32_bf16(ka0, qf0, z, 0, 0, 0);
            st[kf] = __builtin_amdgcn_mfma_f32_16x16x32_bf16(ka1, qf1, z, 0, 0, 0);
        }

        // causal mask (only the diagonal-containing last tile needs it)
        if (t == nkv - 1) {
#pragma unroll
            for (int kf = 0; kf < 4; ++kf) {
#pragma unroll
                for (int r = 0; r < 4; ++r) {
                    int k = kbase + kf * 16 + 4 * g + r;
                    if (k > q) st[kf][r] = -1e30f;
                }
            }
        }

        // online softmax: all 16 of this lane's values belong to q = q0+l15
        float pmax = st[0][0];
#pragma unroll
        for (int kf = 0; kf < 4; ++kf) {
#pragma unroll
            for (int r = 0; r < 4; ++r) pmax = fmaxf(pmax, st[kf][r]);
        }
        pmax = fmaxf(pmax, __shfl_xor(pmax, 16, 64));
        pmax = fmaxf(pmax, __shfl_xor(pmax, 32, 64));
        float mnew = fmaxf(m, pmax);
        float sf = __expf(m - mnew);
        m = mnew;

        float psum = 0.f;
        ushort pb[4][4];
#pragma unroll
        for (int kf = 0; kf < 4; ++kf) {
#pragma unroll
            for (int r = 0; r < 4; ++r) {
                float p = __expf(st[kf][r] - mnew);
                psum += p;
                pb[kf][r] = f2bf(p);
            }
        }
        lsum = lsum * sf + psum;        // lane-partial; reduced at end
#pragma unroll
        for (int i = 0; i < 4; ++i) {
            o[i][0] *= sf; o[i][1] *= sf; o[i][2] *= sf; o[i][3] *= sf;
        }

        // P -> LDS (P[q][k_local], stride 72, double-buffered)
        int buf = t & 1;
#pragma unroll
        for (int kf = 0; kf < 4; ++kf) {
            unsigned w0 = (unsigned)pb[kf][0] | ((unsigned)pb[kf][1] << 16);
            unsigned w1 = (unsigned)pb[kf][2] | ((unsigned)pb[kf][3] << 16);
            *(uint2*)&pl[buf][l15][kf * 16 + 4 * g] = make_uint2(w0, w1);
        }
        __syncthreads();

        // PV: O^T[hf] += VT_frag x P_frag
#pragma unroll
        for (int ks = 0; ks < 2; ++ks) {
            s16x8 pf = *(const s16x8*)&pl[buf][l15][ks * 32 + g * 8];
#pragma unroll
            for (int hf = 0; hf < 4; ++hf) {
                s16x8 vf = *(const s16x8*)(vt + ((size_t)b * 64 + hf * 16 + l15) * TSEQ
                                           + kbase + ks * 32 + g * 8);
                o[hf] = __builtin_amdgcn_mfma_f32_16x16x32_bf16(vf, pf, o[hf], 0, 0, 0);
            }
        }
    }

    // reduce l across the 4 g-groups (lanes sharing the same q)
    lsum += __shfl_xor(lsum, 16, 64);
    lsum += __shfl_xor(lsum, 32, 64);
    float inv = 1.0f / lsum;

    float* orow = out + ((size_t)b * TSEQ + q0 + l15) * 64;
#pragma unroll
    for (int hf = 0; hf < 4; ++hf) {
#pragma unroll
        for (int r = 0; r < 4; ++r)
            orow[hf * 16 + 4 * g + r] = o[hf][r] * inv;
    }
}

extern "C" void kernel_launch(void* const* d_in, const int* in_sizes, int n_in,
                              void* d_out, int out_size, void* d_ws, size_t ws_size,
                              hipStream_t stream) {
    (void)in_sizes; (void)n_in; (void)out_size; (void)ws_size;
    const float* x  = (const float*)d_in[0];
    const float* Wk = (const float*)d_in[1];
    const float* Wq = (const float*)d_in[2];
    const float* Wv = (const float*)d_in[3];
    float* out = (float*)d_out;

    char* ws = (char*)d_ws;
    ushort* wt = (ushort*)(ws);                          // 192*1024*2 = 384 KB
    ushort* qb = (ushort*)(ws + (1u << 20));             // 2 MB
    ushort* kb = (ushort*)(ws + (3u << 20));             // 2 MB
    ushort* vt = (ushort*)(ws + (5u << 20));             // 2 MB

    prep_w<<<48, 256, 0, stream>>>(Wk, Wq, Wv, wt);
    proj<<<1024, 64, 0, stream>>>(x, wt, qb, kb, vt);
    attn<<<1024, 64, 0, stream>>>(qb, kb, vt, out);
}

// Round 3
// 236.032 us; speedup vs baseline: 1.2966x; 1.2966x over previous
//
#include <hip/hip_runtime.h>
#include <hip/hip_bf16.h>

typedef __attribute__((ext_vector_type(8))) short s16x8;
typedef __attribute__((ext_vector_type(4))) float f32x4;

#define TSEQ 4096
#define NW 8

static __device__ __forceinline__ ushort f2bf(float f) {
    union { float f; unsigned u; } v; v.f = f;
    unsigned u = v.u;
    unsigned r = (u + 0x7fffu + ((u >> 16) & 1u)) >> 16;
    return (ushort)r;
}

static __device__ __forceinline__ s16x8 mk8(unsigned a, unsigned b, unsigned c, unsigned d) {
    union { uint4 u; s16x8 v; } x; x.u = make_uint4(a, b, c, d); return x.v;
}

// ---------------- K0: weight prep ----------------
// wt[192][1024] bf16: rows 0-63 = Wq^T (scaled 1/32), 64-127 = Wk^T, 128-191 = Wv^T
__global__ __launch_bounds__(256) void prep_w(const float* __restrict__ Wk,
                                              const float* __restrict__ Wq,
                                              const float* __restrict__ Wv,
                                              ushort* __restrict__ wt) {
    __shared__ float tile[64][65];
    int bid = blockIdx.x;
    int mi = bid >> 4;               // 0=q, 1=k, 2=v
    int e0 = (bid & 15) << 6;
    const float* src = (mi == 0) ? Wq : (mi == 1) ? Wk : Wv;
    int n = threadIdx.x & 63;
    int quad = threadIdx.x >> 6;
#pragma unroll
    for (int r = 0; r < 16; ++r) {
        int el = r * 4 + quad;
        tile[el][n] = src[(size_t)(e0 + el) * 64 + n];
    }
    __syncthreads();
    float scale = (mi == 0) ? 0.03125f : 1.0f;
    int ecol = threadIdx.x & 63;
#pragma unroll
    for (int r = 0; r < 16; ++r) {
        int nl = r * 4 + quad;
        wt[(size_t)(mi * 64 + nl) * 1024 + e0 + ecol] = f2bf(tile[ecol][nl] * scale);
    }
}

// ---------------- K1: QKV projection (4-way E-split) ----------------
__global__ __launch_bounds__(256) void proj(const float* __restrict__ x,
                                            const ushort* __restrict__ wt,
                                            ushort* __restrict__ qb,
                                            ushort* __restrict__ kb,
                                            ushort* __restrict__ vt) {
    __shared__ float part[2][12][64][4];   // 24.6 KB reduction buffer
    __shared__ ushort vtile[16][72];
    int tid = threadIdx.x;
    int lane = tid & 63, w = tid >> 6;
    int l15 = lane & 15, g = lane >> 4;
    size_t m0 = (size_t)blockIdx.x * 16;

    f32x4 acc[12];
#pragma unroll
    for (int i = 0; i < 12; ++i) acc[i] = (f32x4){0.f, 0.f, 0.f, 0.f};

    const float* xrow = x + (m0 + l15) * 1024 + (w << 8);
    const ushort* wb = wt + (w << 8);
#pragma unroll 2
    for (int e0 = 0; e0 < 256; e0 += 32) {
        int e = e0 + g * 8;
        f32x4 xa = *(const f32x4*)(xrow + e);
        f32x4 xb = *(const f32x4*)(xrow + e + 4);
        s16x8 a;
        a[0] = (short)f2bf(xa[0]); a[1] = (short)f2bf(xa[1]);
        a[2] = (short)f2bf(xa[2]); a[3] = (short)f2bf(xa[3]);
        a[4] = (short)f2bf(xb[0]); a[5] = (short)f2bf(xb[1]);
        a[6] = (short)f2bf(xb[2]); a[7] = (short)f2bf(xb[3]);
#pragma unroll
        for (int nf = 0; nf < 12; ++nf) {
            s16x8 b = *(const s16x8*)(wb + (size_t)(l15 + 16 * nf) * 1024 + e);
            acc[nf] = __builtin_amdgcn_mfma_f32_16x16x32_bf16(a, b, acc[nf], 0, 0, 0);
        }
    }

    // pairwise reduction tree: (0+=2, 1+=3), then 0+=1
    if (w >= 2) {
#pragma unroll
        for (int nf = 0; nf < 12; ++nf) *(f32x4*)&part[w - 2][nf][lane][0] = acc[nf];
    }
    __syncthreads();
    if (w < 2) {
#pragma unroll
        for (int nf = 0; nf < 12; ++nf) acc[nf] += *(const f32x4*)&part[w][nf][lane][0];
    }
    __syncthreads();
    if (w == 1) {
#pragma unroll
        for (int nf = 0; nf < 12; ++nf) *(f32x4*)&part[0][nf][lane][0] = acc[nf];
    }
    __syncthreads();
    if (w == 0) {
#pragma unroll
        for (int nf = 0; nf < 12; ++nf) acc[nf] += *(const f32x4*)&part[0][nf][lane][0];

        // q, k stores (C layout: col = l15+16nf, row = m0 + 4g + r)
#pragma unroll
        for (int nf = 0; nf < 4; ++nf) {
#pragma unroll
            for (int r = 0; r < 4; ++r) {
                qb[(m0 + 4 * g + r) * 64 + l15 + 16 * nf] = f2bf(acc[nf][r]);
                kb[(m0 + 4 * g + r) * 64 + l15 + 16 * nf] = f2bf(acc[4 + nf][r]);
            }
        }
        // v transpose through LDS (single-wave: compiler orders aliasing DS ops)
#pragma unroll
        for (int nf = 0; nf < 4; ++nf) {
#pragma unroll
            for (int r = 0; r < 4; ++r)
                vtile[4 * g + r][l15 + 16 * nf] = f2bf(acc[8 + nf][r]);
        }
        unsigned pk[8];
#pragma unroll
        for (int i = 0; i < 8; ++i) {
            unsigned lo = vtile[2 * i][lane];
            unsigned hi = vtile[2 * i + 1][lane];
            pk[i] = lo | (hi << 16);
        }
        size_t b = m0 >> 12;
        size_t t0 = m0 & 4095;
        uint4* dst = (uint4*)(vt + (b * 64 + lane) * TSEQ + t0);
        dst[0] = make_uint4(pk[0], pk[1], pk[2], pk[3]);
        dst[1] = make_uint4(pk[4], pk[5], pk[6], pk[7]);
    }
}

// ---------------- K2: causal flash attention, 8-way KV-split ----------------
// Block = (b, 16-q-row tile), 8 waves. Wave w does KV tiles t ≡ w (mod 8) with
// private online softmax; LDS merge at the end. P stays in registers via the
// slot-permutation trick (A and B share any k<->slot bijection).
__global__ __launch_bounds__(512) void attn(const ushort* __restrict__ qb,
                                            const ushort* __restrict__ kb,
                                            const ushort* __restrict__ vt,
                                            float* __restrict__ out) {
    __shared__ float mrg[NW * 64 * 16];      // 32 KB partial-O merge
    __shared__ float mlb[NW][2][16];         // per-wave m, l
    int tid = threadIdx.x;
    int lane = tid & 63, w = tid >> 6;
    int l15 = lane & 15, g = lane >> 4;
    int bid = blockIdx.x;
    int b = bid & 3;                          // batch -> XCD pinning
    int qt = 255 - (bid >> 2);                // heavy-first
    int q0 = qt << 4;
    int q = q0 + l15;

    const ushort* qbase = qb + ((size_t)b * TSEQ + q0 + l15) * 64;
    s16x8 qf0 = *(const s16x8*)(qbase + g * 8);
    s16x8 qf1 = *(const s16x8*)(qbase + 32 + g * 8);

    f32x4 o[4];
#pragma unroll
    for (int i = 0; i < 4; ++i) o[i] = (f32x4){0.f, 0.f, 0.f, 0.f};
    float m = -1e30f, lsum = 0.f;

    int nkv = (q0 + 79) >> 6;
    for (int t = w; t < nkv; t += NW) {
        int kbase = t << 6;
        const ushort* kt = kb + ((size_t)b * TSEQ + kbase) * 64;

        // QK^T (swapped): st[kf] col q = l15, row k_local = 4g + r
        f32x4 st[4];
#pragma unroll
        for (int kf = 0; kf < 4; ++kf) {
            s16x8 ka0 = *(const s16x8*)(kt + (kf * 16 + l15) * 64 + g * 8);
            s16x8 ka1 = *(const s16x8*)(kt + (kf * 16 + l15) * 64 + 32 + g * 8);
            f32x4 z = (f32x4){0.f, 0.f, 0.f, 0.f};
            z = __builtin_amdgcn_mfma_f32_16x16x32_bf16(ka0, qf0, z, 0, 0, 0);
            st[kf] = __builtin_amdgcn_mfma_f32_16x16x32_bf16(ka1, qf1, z, 0, 0, 0);
        }

        if (t == nkv - 1) {   // only the diagonal tile needs the causal mask
#pragma unroll
            for (int kf = 0; kf < 4; ++kf) {
#pragma unroll
                for (int r = 0; r < 4; ++r) {
                    int k = kbase + kf * 16 + 4 * g + r;
                    if (k > q) st[kf][r] = -1e30f;
                }
            }
        }

        // online softmax for q = q0 + l15 (reduce across the 4 g-groups)
        float pmax = st[0][0];
#pragma unroll
        for (int kf = 0; kf < 4; ++kf) {
#pragma unroll
            for (int r = 0; r < 4; ++r) pmax = fmaxf(pmax, st[kf][r]);
        }
        pmax = fmaxf(pmax, __shfl_xor(pmax, 16, 64));
        pmax = fmaxf(pmax, __shfl_xor(pmax, 32, 64));
        float mnew = fmaxf(m, pmax);
        float sf = __expf(m - mnew);
        m = mnew;

        float psum = 0.f;
        ushort pb[4][4];
#pragma unroll
        for (int kf = 0; kf < 4; ++kf) {
#pragma unroll
            for (int r = 0; r < 4; ++r) {
                float p = __expf(st[kf][r] - mnew);
                psum += p;
                pb[kf][r] = f2bf(p);
            }
        }
        lsum = lsum * sf + psum;
#pragma unroll
        for (int i = 0; i < 4; ++i) {
            o[i][0] *= sf; o[i][1] *= sf; o[i][2] *= sf; o[i][3] *= sf;
        }

        // P stays in registers. Slot bijection pi(g,i) = (i>=4)*16 + 4g + (i&3)
        // applied to BOTH the P (B) and V (A) operands.
        unsigned pw[4][2];
#pragma unroll
        for (int kf = 0; kf < 4; ++kf) {
            pw[kf][0] = (unsigned)pb[kf][0] | ((unsigned)pb[kf][1] << 16);
            pw[kf][1] = (unsigned)pb[kf][2] | ((unsigned)pb[kf][3] << 16);
        }
#pragma unroll
        for (int ks = 0; ks < 2; ++ks) {
            s16x8 pf = mk8(pw[2 * ks][0], pw[2 * ks][1], pw[2 * ks + 1][0], pw[2 * ks + 1][1]);
#pragma unroll
            for (int hf = 0; hf < 4; ++hf) {
                const ushort* vp = vt + ((size_t)b * 64 + hf * 16 + l15) * TSEQ
                                   + kbase + ks * 32 + 4 * g;
                uint2 lo = *(const uint2*)vp;
                uint2 hi = *(const uint2*)(vp + 16);
                s16x8 vf = mk8(lo.x, lo.y, hi.x, hi.y);
                o[hf] = __builtin_amdgcn_mfma_f32_16x16x32_bf16(vf, pf, o[hf], 0, 0, 0);
            }
        }
    }

    // cross-wave merge
    lsum += __shfl_xor(lsum, 16, 64);
    lsum += __shfl_xor(lsum, 32, 64);
#pragma unroll
    for (int hf = 0; hf < 4; ++hf)
        *(f32x4*)&mrg[(w * 64 + lane) * 16 + hf * 4] = o[hf];
    if (lane < 16) {
        mlb[w][0][lane] = m;
        mlb[w][1][lane] = lsum;
    }
    __syncthreads();

    if (w == 0) {
        float M = -1e30f;
#pragma unroll
        for (int ww = 0; ww < NW; ++ww) M = fmaxf(M, mlb[ww][0][l15]);
        float L = 0.f;
        f32x4 oo[4];
#pragma unroll
        for (int i = 0; i < 4; ++i) oo[i] = (f32x4){0.f, 0.f, 0.f, 0.f};
#pragma unroll
        for (int ww = 0; ww < NW; ++ww) {
            float s = __expf(mlb[ww][0][l15] - M);
            L += mlb[ww][1][l15] * s;
#pragma unroll
            for (int hf = 0; hf < 4; ++hf) {
                f32x4 p = *(const f32x4*)&mrg[(ww * 64 + lane) * 16 + hf * 4];
                oo[hf] += p * s;
            }
        }
        float inv = 1.0f / L;
        float* orow = out + ((size_t)b * TSEQ + q0 + l15) * 64;
#pragma unroll
        for (int hf = 0; hf < 4; ++hf) {
            f32x4 r = oo[hf] * inv;
            *(f32x4*)&orow[hf * 16 + 4 * g] = r;
        }
    }
}

extern "C" void kernel_launch(void* const* d_in, const int* in_sizes, int n_in,
                              void* d_out, int out_size, void* d_ws, size_t ws_size,
                              hipStream_t stream) {
    (void)in_sizes; (void)n_in; (void)out_size; (void)ws_size;
    const float* x  = (const float*)d_in[0];
    const float* Wk = (const float*)d_in[1];
    const float* Wq = (const float*)d_in[2];
    const float* Wv = (const float*)d_in[3];
    float* out = (float*)d_out;

    char* ws = (char*)d_ws;
    ushort* wt = (ushort*)(ws);                          // 384 KB
    ushort* qb = (ushort*)(ws + (1u << 20));             // 2 MB
    ushort* kb = (ushort*)(ws + (3u << 20));             // 2 MB
    ushort* vt = (ushort*)(ws + (5u << 20));             // 2 MB

    prep_w<<<48, 256, 0, stream>>>(Wk, Wq, Wv, wt);
    proj<<<1024, 256, 0, stream>>>(x, wt, qb, kb, vt);
    attn<<<1024, 512, 0, stream>>>(qb, kb, vt, out);
}

// Round 4
// 178.963 us; speedup vs baseline: 1.7101x; 1.3189x over previous
//
#include <hip/hip_runtime.h>
#include <hip/hip_bf16.h>

typedef __attribute__((ext_vector_type(8))) short s16x8;
typedef __attribute__((ext_vector_type(4))) float f32x4;

#define TSEQ 4096
#define SPLIT 8

static __device__ __forceinline__ ushort f2bf(float f) {
    union { float f; unsigned u; } v; v.f = f;
    unsigned u = v.u;
    unsigned r = (u + 0x7fffu + ((u >> 16) & 1u)) >> 16;
    return (ushort)r;
}

static __device__ __forceinline__ s16x8 mk8(unsigned a, unsigned b, unsigned c, unsigned d) {
    union { uint4 u; s16x8 v; } x; x.u = make_uint4(a, b, c, d); return x.v;
}

static __device__ __forceinline__ void gload_lds16(const void* g, void* l) {
    __builtin_amdgcn_global_load_lds(
        (const __attribute__((address_space(1))) unsigned int*)g,
        (__attribute__((address_space(3))) unsigned int*)l, 16, 0, 0);
}

// ---------------- K0: weight prep ----------------
// wt[192][1024] bf16: rows 0-63 = Wq^T (scaled 1/32), 64-127 = Wk^T, 128-191 = Wv^T
__global__ __launch_bounds__(256) void prep_w(const float* __restrict__ Wk,
                                              const float* __restrict__ Wq,
                                              const float* __restrict__ Wv,
                                              ushort* __restrict__ wt) {
    __shared__ float tile[64][65];
    int bid = blockIdx.x;
    int mi = bid >> 4;               // 0=q, 1=k, 2=v
    int e0 = (bid & 15) << 6;
    const float* src = (mi == 0) ? Wq : (mi == 1) ? Wk : Wv;
    int n = threadIdx.x & 63;
    int quad = threadIdx.x >> 6;
#pragma unroll
    for (int r = 0; r < 16; ++r) {
        int el = r * 4 + quad;
        tile[el][n] = src[(size_t)(e0 + el) * 64 + n];
    }
    __syncthreads();
    float scale = (mi == 0) ? 0.03125f : 1.0f;
    int ecol = threadIdx.x & 63;
#pragma unroll
    for (int r = 0; r < 16; ++r) {
        int nl = r * 4 + quad;
        wt[(size_t)(mi * 64 + nl) * 1024 + e0 + ecol] = f2bf(tile[ecol][nl] * scale);
    }
}

// ---------------- K1: QKV projection (4-way E-split) ----------------
__global__ __launch_bounds__(256) void proj(const float* __restrict__ x,
                                            const ushort* __restrict__ wt,
                                            ushort* __restrict__ qb,
                                            ushort* __restrict__ kb,
                                            ushort* __restrict__ vt) {
    __shared__ float part[2][12][64][4];
    __shared__ ushort vtile[16][72];
    int tid = threadIdx.x;
    int lane = tid & 63, w = tid >> 6;
    int l15 = lane & 15, g = lane >> 4;
    size_t m0 = (size_t)blockIdx.x * 16;

    f32x4 acc[12];
#pragma unroll
    for (int i = 0; i < 12; ++i) acc[i] = (f32x4){0.f, 0.f, 0.f, 0.f};

    const float* xrow = x + (m0 + l15) * 1024 + (w << 8);
    const ushort* wb = wt + (w << 8);
#pragma unroll 2
    for (int e0 = 0; e0 < 256; e0 += 32) {
        int e = e0 + g * 8;
        f32x4 xa = *(const f32x4*)(xrow + e);
        f32x4 xb = *(const f32x4*)(xrow + e + 4);
        s16x8 a;
        a[0] = (short)f2bf(xa[0]); a[1] = (short)f2bf(xa[1]);
        a[2] = (short)f2bf(xa[2]); a[3] = (short)f2bf(xa[3]);
        a[4] = (short)f2bf(xb[0]); a[5] = (short)f2bf(xb[1]);
        a[6] = (short)f2bf(xb[2]); a[7] = (short)f2bf(xb[3]);
#pragma unroll
        for (int nf = 0; nf < 12; ++nf) {
            s16x8 b = *(const s16x8*)(wb + (size_t)(l15 + 16 * nf) * 1024 + e);
            acc[nf] = __builtin_amdgcn_mfma_f32_16x16x32_bf16(a, b, acc[nf], 0, 0, 0);
        }
    }

    if (w >= 2) {
#pragma unroll
        for (int nf = 0; nf < 12; ++nf) *(f32x4*)&part[w - 2][nf][lane][0] = acc[nf];
    }
    __syncthreads();
    if (w < 2) {
#pragma unroll
        for (int nf = 0; nf < 12; ++nf) acc[nf] += *(const f32x4*)&part[w][nf][lane][0];
    }
    __syncthreads();
    if (w == 1) {
#pragma unroll
        for (int nf = 0; nf < 12; ++nf) *(f32x4*)&part[0][nf][lane][0] = acc[nf];
    }
    __syncthreads();
    if (w == 0) {
#pragma unroll
        for (int nf = 0; nf < 12; ++nf) acc[nf] += *(const f32x4*)&part[0][nf][lane][0];

#pragma unroll
        for (int nf = 0; nf < 4; ++nf) {
#pragma unroll
            for (int r = 0; r < 4; ++r) {
                qb[(m0 + 4 * g + r) * 64 + l15 + 16 * nf] = f2bf(acc[nf][r]);
                kb[(m0 + 4 * g + r) * 64 + l15 + 16 * nf] = f2bf(acc[4 + nf][r]);
            }
        }
#pragma unroll
        for (int nf = 0; nf < 4; ++nf) {
#pragma unroll
            for (int r = 0; r < 4; ++r)
                vtile[4 * g + r][l15 + 16 * nf] = f2bf(acc[8 + nf][r]);
        }
        unsigned pk[8];
#pragma unroll
        for (int i = 0; i < 8; ++i) {
            unsigned lo = vtile[2 * i][lane];
            unsigned hi = vtile[2 * i + 1][lane];
            pk[i] = lo | (hi << 16);
        }
        size_t b = m0 >> 12;
        size_t t0 = m0 & 4095;
        uint4* dst = (uint4*)(vt + (b * 64 + lane) * TSEQ + t0);
        dst[0] = make_uint4(pk[0], pk[1], pk[2], pk[3]);
        dst[1] = make_uint4(pk[4], pk[5], pk[6], pk[7]);
    }
}

// ---------------- K2: flash attention, LDS-staged KV, cross-block KV-split ----------------
// Block = (batch b, 128-row q-panel p, kv-slice s of 8). 8 waves x 16 q-rows.
// K/V 64-tiles staged in LDS (global_load_lds, pre-swizzled source slots),
// double-buffered with raw s_barrier + vmcnt(0). Partials -> workspace.
__global__ __launch_bounds__(512) void attn(const ushort* __restrict__ qb,
                                            const ushort* __restrict__ kb,
                                            const ushort* __restrict__ vt,
                                            float* __restrict__ po,
                                            float2* __restrict__ pml) {
    __shared__ char smem[34816];   // [K0 8K][K1 8K][V0 8K][V1 8K]; reused for O-transpose
    int tid = threadIdx.x;
    int lane = tid & 63, w = tid >> 6;
    int l15 = lane & 15, g = lane >> 4;
    int bid = blockIdx.x;
    int s = bid & 7;
    int b = (bid >> 3) & 3;
    int idx = bid >> 5;                        // 0..31
    int p = (idx < 16) ? (31 - idx) : (idx - 16);   // heavy/light pairing per CU
    int q0w = p * 128 + w * 16;
    int q = q0w + l15;
    int my_tmax = q0w >> 6;
    int nkvb = 2 * p + 2;
    int cnt = (s < nkvb) ? ((nkvb + 7 - s) >> 3) : 0;

    int row = tid >> 3;                        // staging row 0..63
    int kswz = (((tid & 7) ^ (row & 7)) << 3); // pre-swizzled slot (ushorts)

    const ushort* qbase = qb + ((size_t)b * TSEQ + q) * 64;
    s16x8 qf0 = *(const s16x8*)(qbase + g * 8);
    s16x8 qf1 = *(const s16x8*)(qbase + 32 + g * 8);

    f32x4 o[4];
#pragma unroll
    for (int i = 0; i < 4; ++i) o[i] = (f32x4){0.f, 0.f, 0.f, 0.f};
    float m = -1e30f, lsum = 0.f;

#define STAGE(bufsel, tt) do {                                                         \
        const ushort* ksrc_ = kb + ((size_t)b * TSEQ + (size_t)(tt) * 64 + row) * 64 + kswz; \
        gload_lds16(ksrc_, smem + (bufsel) * 8192 + tid * 16);                         \
        const ushort* vsrc_ = vt + ((size_t)b * 64 + row) * TSEQ + (size_t)(tt) * 64 + kswz; \
        gload_lds16(vsrc_, smem + 16384 + (bufsel) * 8192 + tid * 16);                 \
    } while (0)

    if (cnt > 0) {
        STAGE(0, s);
        asm volatile("s_waitcnt vmcnt(0)" ::: "memory");
        __builtin_amdgcn_s_barrier();
        __builtin_amdgcn_sched_barrier(0);
        for (int i = 0; i < cnt; ++i) {
            int t = s + (i << 3);
            int cur = i & 1;
            if (i + 1 < cnt) STAGE(cur ^ 1, t + 8);
            if (t <= my_tmax) {
                const char* Kb = smem + cur * 8192;
                const char* Vb = smem + 16384 + cur * 8192;
                int swz = (l15 & 7) << 4;

                f32x4 st[4];
#pragma unroll
                for (int kf = 0; kf < 4; ++kf) {
                    const char* kr = Kb + (kf * 16 + l15) * 128;
                    s16x8 ka0 = *(const s16x8*)(kr + ((g * 16) ^ swz));
                    s16x8 ka1 = *(const s16x8*)(kr + ((64 + g * 16) ^ swz));
                    f32x4 z = (f32x4){0.f, 0.f, 0.f, 0.f};
                    z = __builtin_amdgcn_mfma_f32_16x16x32_bf16(ka0, qf0, z, 0, 0, 0);
                    st[kf] = __builtin_amdgcn_mfma_f32_16x16x32_bf16(ka1, qf1, z, 0, 0, 0);
                }

                if (t == my_tmax) {
#pragma unroll
                    for (int kf = 0; kf < 4; ++kf) {
#pragma unroll
                        for (int r = 0; r < 4; ++r) {
                            int k = (t << 6) + kf * 16 + 4 * g + r;
                            if (k > q) st[kf][r] = -1e30f;
                        }
                    }
                }

                float pmax = st[0][0];
#pragma unroll
                for (int kf = 0; kf < 4; ++kf) {
#pragma unroll
                    for (int r = 0; r < 4; ++r) pmax = fmaxf(pmax, st[kf][r]);
                }
                pmax = fmaxf(pmax, __shfl_xor(pmax, 16, 64));
                pmax = fmaxf(pmax, __shfl_xor(pmax, 32, 64));
                float mnew = fmaxf(m, pmax);
                float sf = __expf(m - mnew);
                m = mnew;

                float psum = 0.f;
                ushort pb[4][4];
#pragma unroll
                for (int kf = 0; kf < 4; ++kf) {
#pragma unroll
                    for (int r = 0; r < 4; ++r) {
                        float pv = __expf(st[kf][r] - mnew);
                        psum += pv;
                        pb[kf][r] = f2bf(pv);
                    }
                }
                lsum = lsum * sf + psum;
#pragma unroll
                for (int i2 = 0; i2 < 4; ++i2) {
                    o[i2][0] *= sf; o[i2][1] *= sf; o[i2][2] *= sf; o[i2][3] *= sf;
                }

                unsigned pw[4][2];
#pragma unroll
                for (int kf = 0; kf < 4; ++kf) {
                    pw[kf][0] = (unsigned)pb[kf][0] | ((unsigned)pb[kf][1] << 16);
                    pw[kf][1] = (unsigned)pb[kf][2] | ((unsigned)pb[kf][3] << 16);
                }
#pragma unroll
                for (int ks = 0; ks < 2; ++ks) {
                    s16x8 pf = mk8(pw[2 * ks][0], pw[2 * ks][1], pw[2 * ks + 1][0], pw[2 * ks + 1][1]);
#pragma unroll
                    for (int hf = 0; hf < 4; ++hf) {
                        const char* vr = Vb + (hf * 16 + l15) * 128;
                        uint2 lo = *(const uint2*)(vr + ((ks * 64 + g * 8) ^ swz));
                        uint2 hi = *(const uint2*)(vr + ((ks * 64 + 32 + g * 8) ^ swz));
                        o[hf] = __builtin_amdgcn_mfma_f32_16x16x32_bf16(
                            mk8(lo.x, lo.y, hi.x, hi.y), pf, o[hf], 0, 0, 0);
                    }
                }
            }
            __builtin_amdgcn_sched_barrier(0);
            asm volatile("s_waitcnt vmcnt(0)" ::: "memory");
            __builtin_amdgcn_s_barrier();
            __builtin_amdgcn_sched_barrier(0);
        }
    }
#undef STAGE

    __syncthreads();   // staging done everywhere; reuse smem for transpose

    lsum += __shfl_xor(lsum, 16, 64);
    lsum += __shfl_xor(lsum, 32, 64);

    // transpose O^T (16 q-rows x 64 h) through per-wave LDS region, store coalesced
    float* ot = (float*)(smem + w * 4352);     // 16 x 68 floats
#pragma unroll
    for (int hf = 0; hf < 4; ++hf) {
#pragma unroll
        for (int r = 0; r < 4; ++r)
            ot[l15 * 68 + hf * 16 + 4 * g + r] = o[hf][r];
    }
    int rowq = lane >> 2, quad = lane & 3;
    size_t obase = ((size_t)s * 16384 + b * 4096 + q0w + rowq) * 64 + quad * 16;
#pragma unroll
    for (int j = 0; j < 4; ++j) {
        f32x4 vv = *(const f32x4*)&ot[rowq * 68 + quad * 16 + j * 4];
        *(f32x4*)(po + obase + j * 4) = vv;
    }
    if (lane < 16) {
        pml[(size_t)s * 16384 + b * 4096 + q0w + l15] = make_float2(m, lsum);
    }
}

// ---------------- K3: merge KV-split partials ----------------
__global__ __launch_bounds__(256) void merge(const float* __restrict__ po,
                                             const float2* __restrict__ pml,
                                             float* __restrict__ out) {
    int gt = blockIdx.x * 256 + threadIdx.x;   // 0 .. 262143
    int rowq = gt >> 4;                         // b*4096 + t
    int h4 = (gt & 15) << 2;
    float ms[SPLIT], ls[SPLIT];
    float M = -1e30f;
#pragma unroll
    for (int s2 = 0; s2 < SPLIT; ++s2) {
        float2 ml = pml[(size_t)s2 * 16384 + rowq];
        ms[s2] = ml.x; ls[s2] = ml.y;
        M = fmaxf(M, ml.x);
    }
    float L = 0.f;
    float ww[SPLIT];
#pragma unroll
    for (int s2 = 0; s2 < SPLIT; ++s2) {
        float e = __expf(ms[s2] - M);
        ww[s2] = e;
        L += ls[s2] * e;
    }
    f32x4 acc = (f32x4){0.f, 0.f, 0.f, 0.f};
#pragma unroll
    for (int s2 = 0; s2 < SPLIT; ++s2) {
        f32x4 v = *(const f32x4*)(po + ((size_t)s2 * 16384 + rowq) * 64 + h4);
        acc += v * ww[s2];
    }
    float inv = 1.0f / L;
    *(f32x4*)(out + (size_t)rowq * 64 + h4) = acc * inv;
}

extern "C" void kernel_launch(void* const* d_in, const int* in_sizes, int n_in,
                              void* d_out, int out_size, void* d_ws, size_t ws_size,
                              hipStream_t stream) {
    (void)in_sizes; (void)n_in; (void)out_size; (void)ws_size;
    const float* x  = (const float*)d_in[0];
    const float* Wk = (const float*)d_in[1];
    const float* Wq = (const float*)d_in[2];
    const float* Wv = (const float*)d_in[3];
    float* out = (float*)d_out;

    char* ws = (char*)d_ws;
    ushort* wt = (ushort*)(ws);                          // 384 KB
    ushort* qb = (ushort*)(ws + (1u << 20));             // 2 MB
    ushort* kb = (ushort*)(ws + (3u << 20));             // 2 MB
    ushort* vt = (ushort*)(ws + (5u << 20));             // 2 MB
    float*  po = (float*)(ws + ((size_t)8 << 20));       // 32 MB partial O
    float2* pml = (float2*)(ws + ((size_t)40 << 20));    // 1 MB partial m,l

    prep_w<<<48, 256, 0, stream>>>(Wk, Wq, Wv, wt);
    proj<<<1024, 256, 0, stream>>>(x, wt, qb, kb, vt);
    attn<<<1024, 512, 0, stream>>>(qb, kb, vt, po, pml);
    merge<<<1024, 256, 0, stream>>>(po, pml, out);
}

// Round 5
// 176.212 us; speedup vs baseline: 1.7368x; 1.0156x over previous
//
#include <hip/hip_runtime.h>
#include <hip/hip_bf16.h>

typedef __attribute__((ext_vector_type(8))) short s16x8;
typedef __attribute__((ext_vector_type(4))) float f32x4;

#define TSEQ 4096
#define SPLIT 8

static __device__ __forceinline__ ushort f2bf(float f) {
    union { float f; unsigned u; } v; v.f = f;
    unsigned u = v.u;
    unsigned r = (u + 0x7fffu + ((u >> 16) & 1u)) >> 16;
    return (ushort)r;
}

static __device__ __forceinline__ s16x8 mk8(unsigned a, unsigned b, unsigned c, unsigned d) {
    union { uint4 u; s16x8 v; } x; x.u = make_uint4(a, b, c, d); return x.v;
}

static __device__ __forceinline__ void gload_lds16(const void* g, void* l) {
    __builtin_amdgcn_global_load_lds(
        (const __attribute__((address_space(1))) unsigned int*)g,
        (__attribute__((address_space(3))) unsigned int*)l, 16, 0, 0);
}

// ---------------- K0: weight prep ----------------
// wt[192][1024] bf16: rows 0-63 = Wq^T (scaled 1/32), 64-127 = Wk^T, 128-191 = Wv^T
__global__ __launch_bounds__(256) void prep_w(const float* __restrict__ Wk,
                                              const float* __restrict__ Wq,
                                              const float* __restrict__ Wv,
                                              ushort* __restrict__ wt) {
    __shared__ float tile[64][65];
    int bid = blockIdx.x;
    int mi = bid >> 4;               // 0=q, 1=k, 2=v
    int e0 = (bid & 15) << 6;
    const float* src = (mi == 0) ? Wq : (mi == 1) ? Wk : Wv;
    int n = threadIdx.x & 63;
    int quad = threadIdx.x >> 6;
#pragma unroll
    for (int r = 0; r < 16; ++r) {
        int el = r * 4 + quad;
        tile[el][n] = src[(size_t)(e0 + el) * 64 + n];
    }
    __syncthreads();
    float scale = (mi == 0) ? 0.03125f : 1.0f;
    int ecol = threadIdx.x & 63;
#pragma unroll
    for (int r = 0; r < 16; ++r) {
        int nl = r * 4 + quad;
        wt[(size_t)(mi * 64 + nl) * 1024 + e0 + ecol] = f2bf(tile[ecol][nl] * scale);
    }
}

// ---------------- K1: QKV projection (2-phase pipelined, N-split) ----------------
// Block: 16 rows x N=192, 4 waves, wave w owns nf = 3w..3w+2. x-tile staged in
// LDS via global_load_lds (pre-swizzled source, slot ^= row), double-buffered.
__global__ __launch_bounds__(256) void proj(const float* __restrict__ x,
                                            const ushort* __restrict__ wt,
                                            ushort* __restrict__ qb,
                                            ushort* __restrict__ kb,
                                            ushort* __restrict__ vt) {
    __shared__ char xs[2][4096];     // 16 rows x 64 K f32, swizzled 16B slots
    int tid = threadIdx.x;
    int lane = tid & 63, w = tid >> 6;
    int l15 = lane & 15, g = lane >> 4;
    size_t m0 = (size_t)blockIdx.x * 16;
    int nfb = 3 * w;

    int srow = tid >> 4;             // 0..15
    int sslot = tid & 15;
    const float* xsrc = x + (m0 + srow) * 1024 + ((sslot ^ srow) << 2);

    f32x4 acc[3];
#pragma unroll
    for (int j = 0; j < 3; ++j) acc[j] = (f32x4){0.f, 0.f, 0.f, 0.f};

    const ushort* wrow[3];
#pragma unroll
    for (int j = 0; j < 3; ++j)
        wrow[j] = wt + (size_t)(l15 + 16 * (nfb + j)) * 1024;

#define PSTAGE(bufsel, it) gload_lds16(xsrc + ((it) << 6), xs[bufsel] + tid * 16)

    PSTAGE(0, 0);
    asm volatile("s_waitcnt vmcnt(0)" ::: "memory");
    __builtin_amdgcn_s_barrier();
    __builtin_amdgcn_sched_barrier(0);
    for (int i = 0; i < 16; ++i) {
        int cur = i & 1;
        if (i + 1 < 16) PSTAGE(cur ^ 1, i + 1);
        const char* Xb = xs[cur];
        int k0 = i << 6;
#pragma unroll
        for (int ks = 0; ks < 2; ++ks) {
            int s0 = ks * 8 + g * 2;
            f32x4 xa = *(const f32x4*)(Xb + l15 * 256 + ((s0 ^ l15) << 4));
            f32x4 xb2 = *(const f32x4*)(Xb + l15 * 256 + (((s0 + 1) ^ l15) << 4));
            s16x8 a;
#pragma unroll
            for (int q2 = 0; q2 < 4; ++q2) {
                a[q2] = (short)__bfloat16_as_ushort(__float2bfloat16(xa[q2]));
                a[q2 + 4] = (short)__bfloat16_as_ushort(__float2bfloat16(xb2[q2]));
            }
#pragma unroll
            for (int j = 0; j < 3; ++j) {
                s16x8 bf = *(const s16x8*)(wrow[j] + k0 + ks * 32 + g * 8);
                acc[j] = __builtin_amdgcn_mfma_f32_16x16x32_bf16(a, bf, acc[j], 0, 0, 0);
            }
        }
        __builtin_amdgcn_sched_barrier(0);
        asm volatile("s_waitcnt vmcnt(0)" ::: "memory");
        __builtin_amdgcn_s_barrier();
        __builtin_amdgcn_sched_barrier(0);
    }
#undef PSTAGE

    // epilogue: each wave stores its own 3 nf fragments
#pragma unroll
    for (int j = 0; j < 3; ++j) {
        int nf = nfb + j;
        if (nf < 4) {
#pragma unroll
            for (int r = 0; r < 4; ++r)
                qb[(m0 + 4 * g + r) * 64 + l15 + 16 * nf] = f2bf(acc[j][r]);
        } else if (nf < 8) {
#pragma unroll
            for (int r = 0; r < 4; ++r)
                kb[(m0 + 4 * g + r) * 64 + l15 + 16 * (nf - 4)] = f2bf(acc[j][r]);
        } else {
            int h = l15 + 16 * (nf - 8);
            size_t b = m0 >> 12;
            size_t t0 = (m0 & 4095) + 4 * g;
            unsigned w0 = (unsigned)f2bf(acc[j][0]) | ((unsigned)f2bf(acc[j][1]) << 16);
            unsigned w1 = (unsigned)f2bf(acc[j][2]) | ((unsigned)f2bf(acc[j][3]) << 16);
            *(uint2*)(vt + (b * 64 + h) * TSEQ + t0) = make_uint2(w0, w1);
        }
    }
}

// ---------------- K2: flash attention, LDS-staged KV, cross-block KV-split ----------------
// Block = (batch b, 128-row q-panel p, kv-slice s of 8). 8 waves x 16 q-rows.
// K/V 64-tiles staged in LDS (global_load_lds, pre-swizzled source slots),
// double-buffered with raw s_barrier + vmcnt(0). Partials -> workspace.
__global__ __launch_bounds__(512) void attn(const ushort* __restrict__ qb,
                                            const ushort* __restrict__ kb,
                                            const ushort* __restrict__ vt,
                                            float* __restrict__ po,
                                            float2* __restrict__ pml) {
    __shared__ char smem[34816];   // [K0 8K][K1 8K][V0 8K][V1 8K]; reused for O-transpose
    int tid = threadIdx.x;
    int lane = tid & 63, w = tid >> 6;
    int l15 = lane & 15, g = lane >> 4;
    int bid = blockIdx.x;
    int s = bid & 7;
    int b = (bid >> 3) & 3;
    int idx = bid >> 5;                        // 0..31
    int p = (idx < 16) ? (31 - idx) : (idx - 16);   // heavy/light pairing per CU
    int q0w = p * 128 + w * 16;
    int q = q0w + l15;
    int my_tmax = q0w >> 6;
    int nkvb = 2 * p + 2;
    int cnt = (s < nkvb) ? ((nkvb + 7 - s) >> 3) : 0;

    int row = tid >> 3;                        // staging row 0..63
    int kswz = (((tid & 7) ^ (row & 7)) << 3); // pre-swizzled slot (ushorts)

    const ushort* qbase = qb + ((size_t)b * TSEQ + q) * 64;
    s16x8 qf0 = *(const s16x8*)(qbase + g * 8);
    s16x8 qf1 = *(const s16x8*)(qbase + 32 + g * 8);

    f32x4 o[4];
#pragma unroll
    for (int i = 0; i < 4; ++i) o[i] = (f32x4){0.f, 0.f, 0.f, 0.f};
    float m = -1e30f, lsum = 0.f;

#define STAGE(bufsel, tt) do {                                                         \
        const ushort* ksrc_ = kb + ((size_t)b * TSEQ + (size_t)(tt) * 64 + row) * 64 + kswz; \
        gload_lds16(ksrc_, smem + (bufsel) * 8192 + tid * 16);                         \
        const ushort* vsrc_ = vt + ((size_t)b * 64 + row) * TSEQ + (size_t)(tt) * 64 + kswz; \
        gload_lds16(vsrc_, smem + 16384 + (bufsel) * 8192 + tid * 16);                 \
    } while (0)

    if (cnt > 0) {
        STAGE(0, s);
        asm volatile("s_waitcnt vmcnt(0)" ::: "memory");
        __builtin_amdgcn_s_barrier();
        __builtin_amdgcn_sched_barrier(0);
        for (int i = 0; i < cnt; ++i) {
            int t = s + (i << 3);
            int cur = i & 1;
            if (i + 1 < cnt) STAGE(cur ^ 1, t + 8);
            if (t <= my_tmax) {
                const char* Kb = smem + cur * 8192;
                const char* Vb = smem + 16384 + cur * 8192;
                int swz = (l15 & 7) << 4;

                f32x4 st[4];
#pragma unroll
                for (int kf = 0; kf < 4; ++kf) {
                    const char* kr = Kb + (kf * 16 + l15) * 128;
                    s16x8 ka0 = *(const s16x8*)(kr + ((g * 16) ^ swz));
                    s16x8 ka1 = *(const s16x8*)(kr + ((64 + g * 16) ^ swz));
                    f32x4 z = (f32x4){0.f, 0.f, 0.f, 0.f};
                    z = __builtin_amdgcn_mfma_f32_16x16x32_bf16(ka0, qf0, z, 0, 0, 0);
                    st[kf] = __builtin_amdgcn_mfma_f32_16x16x32_bf16(ka1, qf1, z, 0, 0, 0);
                }

                if (t == my_tmax) {
#pragma unroll
                    for (int kf = 0; kf < 4; ++kf) {
#pragma unroll
                        for (int r = 0; r < 4; ++r) {
                            int k = (t << 6) + kf * 16 + 4 * g + r;
                            if (k > q) st[kf][r] = -1e30f;
                        }
                    }
                }

                float pmax = st[0][0];
#pragma unroll
                for (int kf = 0; kf < 4; ++kf) {
#pragma unroll
                    for (int r = 0; r < 4; ++r) pmax = fmaxf(pmax, st[kf][r]);
                }
                pmax = fmaxf(pmax, __shfl_xor(pmax, 16, 64));
                pmax = fmaxf(pmax, __shfl_xor(pmax, 32, 64));
                float mnew = fmaxf(m, pmax);
                float sf = __expf(m - mnew);
                m = mnew;

                float psum = 0.f;
                ushort pb[4][4];
#pragma unroll
                for (int kf = 0; kf < 4; ++kf) {
#pragma unroll
                    for (int r = 0; r < 4; ++r) {
                        float pv = __expf(st[kf][r] - mnew);
                        psum += pv;
                        pb[kf][r] = f2bf(pv);
                    }
                }
                lsum = lsum * sf + psum;
#pragma unroll
                for (int i2 = 0; i2 < 4; ++i2) {
                    o[i2][0] *= sf; o[i2][1] *= sf; o[i2][2] *= sf; o[i2][3] *= sf;
                }

                unsigned pw[4][2];
#pragma unroll
                for (int kf = 0; kf < 4; ++kf) {
                    pw[kf][0] = (unsigned)pb[kf][0] | ((unsigned)pb[kf][1] << 16);
                    pw[kf][1] = (unsigned)pb[kf][2] | ((unsigned)pb[kf][3] << 16);
                }
#pragma unroll
                for (int ks = 0; ks < 2; ++ks) {
                    s16x8 pf = mk8(pw[2 * ks][0], pw[2 * ks][1], pw[2 * ks + 1][0], pw[2 * ks + 1][1]);
#pragma unroll
                    for (int hf = 0; hf < 4; ++hf) {
                        const char* vr = Vb + (hf * 16 + l15) * 128;
                        uint2 lo = *(const uint2*)(vr + ((ks * 64 + g * 8) ^ swz));
                        uint2 hi = *(const uint2*)(vr + ((ks * 64 + 32 + g * 8) ^ swz));
                        o[hf] = __builtin_amdgcn_mfma_f32_16x16x32_bf16(
                            mk8(lo.x, lo.y, hi.x, hi.y), pf, o[hf], 0, 0, 0);
                    }
                }
            }
            __builtin_amdgcn_sched_barrier(0);
            asm volatile("s_waitcnt vmcnt(0)" ::: "memory");
            __builtin_amdgcn_s_barrier();
            __builtin_amdgcn_sched_barrier(0);
        }
    }
#undef STAGE

    __syncthreads();   // staging done everywhere; reuse smem for transpose

    lsum += __shfl_xor(lsum, 16, 64);
    lsum += __shfl_xor(lsum, 32, 64);

    // transpose O^T (16 q-rows x 64 h) through per-wave LDS region, store coalesced
    float* ot = (float*)(smem + w * 4352);     // 16 x 68 floats
#pragma unroll
    for (int hf = 0; hf < 4; ++hf) {
#pragma unroll
        for (int r = 0; r < 4; ++r)
            ot[l15 * 68 + hf * 16 + 4 * g + r] = o[hf][r];
    }
    int rowq = lane >> 2, quad = lane & 3;
    size_t obase = ((size_t)s * 16384 + b * 4096 + q0w + rowq) * 64 + quad * 16;
#pragma unroll
    for (int j = 0; j < 4; ++j) {
        f32x4 vv = *(const f32x4*)&ot[rowq * 68 + quad * 16 + j * 4];
        *(f32x4*)(po + obase + j * 4) = vv;
    }
    if (lane < 16) {
        pml[(size_t)s * 16384 + b * 4096 + q0w + l15] = make_float2(m, lsum);
    }
}

// ---------------- K3: merge KV-split partials ----------------
__global__ __launch_bounds__(256) void merge(const float* __restrict__ po,
                                             const float2* __restrict__ pml,
                                             float* __restrict__ out) {
    int gt = blockIdx.x * 256 + threadIdx.x;   // 0 .. 262143
    int rowq = gt >> 4;                         // b*4096 + t
    int h4 = (gt & 15) << 2;
    float ms[SPLIT], ls[SPLIT];
    float M = -1e30f;
#pragma unroll
    for (int s2 = 0; s2 < SPLIT; ++s2) {
        float2 ml = pml[(size_t)s2 * 16384 + rowq];
        ms[s2] = ml.x; ls[s2] = ml.y;
        M = fmaxf(M, ml.x);
    }
    float L = 0.f;
    float ww[SPLIT];
#pragma unroll
    for (int s2 = 0; s2 < SPLIT; ++s2) {
        float e = __expf(ms[s2] - M);
        ww[s2] = e;
        L += ls[s2] * e;
    }
    f32x4 acc = (f32x4){0.f, 0.f, 0.f, 0.f};
#pragma unroll
    for (int s2 = 0; s2 < SPLIT; ++s2) {
        f32x4 v = *(const f32x4*)(po + ((size_t)s2 * 16384 + rowq) * 64 + h4);
        acc += v * ww[s2];
    }
    float inv = 1.0f / L;
    *(f32x4*)(out + (size_t)rowq * 64 + h4) = acc * inv;
}

extern "C" void kernel_launch(void* const* d_in, const int* in_sizes, int n_in,
                              void* d_out, int out_size, void* d_ws, size_t ws_size,
                              hipStream_t stream) {
    (void)in_sizes; (void)n_in; (void)out_size; (void)ws_size;
    const float* x  = (const float*)d_in[0];
    const float* Wk = (const float*)d_in[1];
    const float* Wq = (const float*)d_in[2];
    const float* Wv = (const float*)d_in[3];
    float* out = (float*)d_out;

    char* ws = (char*)d_ws;
    ushort* wt = (ushort*)(ws);                          // 384 KB
    ushort* qb = (ushort*)(ws + (1u << 20));             // 2 MB
    ushort* kb = (ushort*)(ws + (3u << 20));             // 2 MB
    ushort* vt = (ushort*)(ws + (5u << 20));             // 2 MB
    float*  po = (float*)(ws + ((size_t)8 << 20));       // 32 MB partial O
    float2* pml = (float2*)(ws + ((size_t)40 << 20));    // 1 MB partial m,l

    prep_w<<<48, 256, 0, stream>>>(Wk, Wq, Wv, wt);
    proj<<<1024, 256, 0, stream>>>(x, wt, qb, kb, vt);
    attn<<<1024, 512, 0, stream>>>(qb, kb, vt, po, pml);
    merge<<<1024, 256, 0, stream>>>(po, pml, out);
}

// Round 6
// 142.247 us; speedup vs baseline: 2.1515x; 1.2388x over previous
//
#include <hip/hip_runtime.h>
#include <hip/hip_bf16.h>

typedef __attribute__((ext_vector_type(8))) short s16x8;
typedef __attribute__((ext_vector_type(4))) float f32x4;

#define TSEQ 4096
#define SPLIT 8

static __device__ __forceinline__ ushort f2bf(float f) {
    union { float f; unsigned u; } v; v.f = f;
    unsigned u = v.u;
    unsigned r = (u + 0x7fffu + ((u >> 16) & 1u)) >> 16;
    return (ushort)r;
}

static __device__ __forceinline__ s16x8 mk8(unsigned a, unsigned b, unsigned c, unsigned d) {
    union { uint4 u; s16x8 v; } x; x.u = make_uint4(a, b, c, d); return x.v;
}

static __device__ __forceinline__ void gload_lds16(const void* g, void* l) {
    __builtin_amdgcn_global_load_lds(
        (const __attribute__((address_space(1))) unsigned int*)g,
        (__attribute__((address_space(3))) unsigned int*)l, 16, 0, 0);
}

// ---------------- K0: weight prep ----------------
// wt[192][1024] bf16: rows 0-63 = Wq^T (scaled 1/32), 64-127 = Wk^T, 128-191 = Wv^T
__global__ __launch_bounds__(256) void prep_w(const float* __restrict__ Wk,
                                              const float* __restrict__ Wq,
                                              const float* __restrict__ Wv,
                                              ushort* __restrict__ wt) {
    __shared__ float tile[64][65];
    int bid = blockIdx.x;
    int mi = bid >> 4;               // 0=q, 1=k, 2=v
    int e0 = (bid & 15) << 6;
    const float* src = (mi == 0) ? Wq : (mi == 1) ? Wk : Wv;
    int n = threadIdx.x & 63;
    int quad = threadIdx.x >> 6;
#pragma unroll
    for (int r = 0; r < 16; ++r) {
        int el = r * 4 + quad;
        tile[el][n] = src[(size_t)(e0 + el) * 64 + n];
    }
    __syncthreads();
    float scale = (mi == 0) ? 0.03125f : 1.0f;
    int ecol = threadIdx.x & 63;
#pragma unroll
    for (int r = 0; r < 16; ++r) {
        int nl = r * 4 + quad;
        wt[(size_t)(mi * 64 + nl) * 1024 + e0 + ecol] = f2bf(tile[ecol][nl] * scale);
    }
}

// ---------------- K1: QKV projection, 3-deep DMA pipeline ----------------
// 256 blocks x 8 waves. Block: M=64 rows, N=192, K=1024, BK=64 (16 steps).
// Per step: x-tile 16 KB + wt-tile 24 KB staged via global_load_lds into a
// 3-buffer ring; counted vmcnt(5) keeps 2 tiles in flight (never drains).
// Both tiles XOR-swizzled via pre-swizzled global source.
__global__ __launch_bounds__(512) void proj(const float* __restrict__ x,
                                            const ushort* __restrict__ wt,
                                            ushort* __restrict__ qb,
                                            ushort* __restrict__ kb,
                                            ushort* __restrict__ vt) {
    __shared__ char smem[3 * 40960];     // per buf: [A 16K f32][B 24K bf16]
    int tid = threadIdx.x;
    int lane = tid & 63, w = tid >> 6;
    int l15 = lane & 15, g = lane >> 4;
    int mh = w >> 2, nq = w & 3;         // wave tile: rows mh*32+..., cols nq*48+...
    size_t m0 = (size_t)blockIdx.x * 64;

    // staging sources (pre-swizzled so LDS stays linear)
    int rA = tid >> 4, sA = tid & 15;
    const float* xsrc = x + (m0 + rA) * 1024 + ((sA ^ (rA & 15)) << 2);
    int rB = tid >> 3, sB = tid & 7;
    const ushort* wsrc = wt + (size_t)rB * 1024 + ((sB ^ (rB & 7)) << 3);

    f32x4 acc[2][3];
#pragma unroll
    for (int mi = 0; mi < 2; ++mi)
#pragma unroll
        for (int j = 0; j < 3; ++j) acc[mi][j] = (f32x4){0.f, 0.f, 0.f, 0.f};

#define PSTAGE(bufsel, it) do {                                        \
        size_t k0_ = (size_t)(it) << 6;                                \
        char* bb_ = smem + (bufsel) * 40960;                           \
        gload_lds16(xsrc + k0_, bb_ + tid * 16);                       \
        gload_lds16(xsrc + 32 * 1024 + k0_, bb_ + 8192 + tid * 16);    \
        gload_lds16(wsrc + k0_, bb_ + 16384 + tid * 16);               \
        gload_lds16(wsrc + 64 * 1024 + k0_, bb_ + 24576 + tid * 16);   \
        gload_lds16(wsrc + 128 * 1024 + k0_, bb_ + 32768 + tid * 16);  \
    } while (0)

    PSTAGE(0, 0);
    PSTAGE(1, 1);
    for (int i = 0; i < 16; ++i) {
        int cur = i % 3;
        __builtin_amdgcn_sched_barrier(0);
        if (i < 15) asm volatile("s_waitcnt vmcnt(5)" ::: "memory");
        else        asm volatile("s_waitcnt vmcnt(0)" ::: "memory");
        __builtin_amdgcn_s_barrier();
        __builtin_amdgcn_sched_barrier(0);
        if (i + 2 < 16) PSTAGE((i + 2) % 3, i + 2);   // overwrites buf read in iter i-1 (safe: barrier above)

        const char* Ab = smem + cur * 40960;
        const char* Bb = Ab + 16384;
#pragma unroll
        for (int ks = 0; ks < 2; ++ks) {
            s16x8 a[2];
#pragma unroll
            for (int mi = 0; mi < 2; ++mi) {
                int row = mh * 32 + mi * 16 + l15;
                int s0 = ks * 8 + g * 2;
                f32x4 xa = *(const f32x4*)(Ab + row * 256 + ((s0 ^ l15) << 4));
                f32x4 xb2 = *(const f32x4*)(Ab + row * 256 + (((s0 + 1) ^ l15) << 4));
#pragma unroll
                for (int q2 = 0; q2 < 4; ++q2) {
                    a[mi][q2] = (short)f2bf(xa[q2]);
                    a[mi][q2 + 4] = (short)f2bf(xb2[q2]);
                }
            }
#pragma unroll
            for (int j = 0; j < 3; ++j) {
                int n = nq * 48 + j * 16 + l15;
                s16x8 bf = *(const s16x8*)(Bb + n * 128 + (((ks * 4 + g) ^ (l15 & 7)) << 4));
#pragma unroll
                for (int mi = 0; mi < 2; ++mi)
                    acc[mi][j] = __builtin_amdgcn_mfma_f32_16x16x32_bf16(a[mi], bf, acc[mi][j], 0, 0, 0);
            }
        }
    }
#undef PSTAGE

    // epilogue: wave-owned stores (C layout: col = n, row = base + 4g + r)
    size_t bb = m0 >> 12;
    size_t t00 = m0 & 4095;
#pragma unroll
    for (int mi = 0; mi < 2; ++mi) {
        size_t Mb = m0 + mh * 32 + mi * 16 + 4 * g;
#pragma unroll
        for (int j = 0; j < 3; ++j) {
            int nf = nq * 3 + j;
            int n = nf * 16 + l15;
            if (nf < 4) {
#pragma unroll
                for (int r = 0; r < 4; ++r)
                    qb[(Mb + r) * 64 + n] = f2bf(acc[mi][j][r]);
            } else if (nf < 8) {
#pragma unroll
                for (int r = 0; r < 4; ++r)
                    kb[(Mb + r) * 64 + (n - 64)] = f2bf(acc[mi][j][r]);
            } else {
                int h = n - 128;
                size_t tloc = t00 + mh * 32 + mi * 16 + 4 * g;
                unsigned w0 = (unsigned)f2bf(acc[mi][j][0]) | ((unsigned)f2bf(acc[mi][j][1]) << 16);
                unsigned w1 = (unsigned)f2bf(acc[mi][j][2]) | ((unsigned)f2bf(acc[mi][j][3]) << 16);
                *(uint2*)(vt + (bb * 64 + h) * TSEQ + tloc) = make_uint2(w0, w1);
            }
        }
    }
}

// ---------------- K2: flash attention, LDS-staged KV, cross-block KV-split ----------------
__global__ __launch_bounds__(512) void attn(const ushort* __restrict__ qb,
                                            const ushort* __restrict__ kb,
                                            const ushort* __restrict__ vt,
                                            float* __restrict__ po,
                                            float2* __restrict__ pml) {
    __shared__ char smem[34816];   // [K0 8K][K1 8K][V0 8K][V1 8K]; reused for O-transpose
    int tid = threadIdx.x;
    int lane = tid & 63, w = tid >> 6;
    int l15 = lane & 15, g = lane >> 4;
    int bid = blockIdx.x;
    int s = bid & 7;
    int b = (bid >> 3) & 3;
    int idx = bid >> 5;                        // 0..31
    int p = (idx < 16) ? (31 - idx) : (idx - 16);   // heavy/light pairing per CU
    int q0w = p * 128 + w * 16;
    int q = q0w + l15;
    int my_tmax = q0w >> 6;
    int nkvb = 2 * p + 2;
    int cnt = (s < nkvb) ? ((nkvb + 7 - s) >> 3) : 0;

    int row = tid >> 3;                        // staging row 0..63
    int kswz = (((tid & 7) ^ (row & 7)) << 3); // pre-swizzled slot (ushorts)

    const ushort* qbase = qb + ((size_t)b * TSEQ + q) * 64;
    s16x8 qf0 = *(const s16x8*)(qbase + g * 8);
    s16x8 qf1 = *(const s16x8*)(qbase + 32 + g * 8);

    f32x4 o[4];
#pragma unroll
    for (int i = 0; i < 4; ++i) o[i] = (f32x4){0.f, 0.f, 0.f, 0.f};
    float m = -1e30f, lsum = 0.f;

#define STAGE(bufsel, tt) do {                                                         \
        const ushort* ksrc_ = kb + ((size_t)b * TSEQ + (size_t)(tt) * 64 + row) * 64 + kswz; \
        gload_lds16(ksrc_, smem + (bufsel) * 8192 + tid * 16);                         \
        const ushort* vsrc_ = vt + ((size_t)b * 64 + row) * TSEQ + (size_t)(tt) * 64 + kswz; \
        gload_lds16(vsrc_, smem + 16384 + (bufsel) * 8192 + tid * 16);                 \
    } while (0)

    if (cnt > 0) {
        STAGE(0, s);
        asm volatile("s_waitcnt vmcnt(0)" ::: "memory");
        __builtin_amdgcn_s_barrier();
        __builtin_amdgcn_sched_barrier(0);
        for (int i = 0; i < cnt; ++i) {
            int t = s + (i << 3);
            int cur = i & 1;
            if (i + 1 < cnt) STAGE(cur ^ 1, t + 8);
            if (t <= my_tmax) {
                const char* Kb = smem + cur * 8192;
                const char* Vb = smem + 16384 + cur * 8192;
                int swz = (l15 & 7) << 4;

                f32x4 st[4];
#pragma unroll
                for (int kf = 0; kf < 4; ++kf) {
                    const char* kr = Kb + (kf * 16 + l15) * 128;
                    s16x8 ka0 = *(const s16x8*)(kr + ((g * 16) ^ swz));
                    s16x8 ka1 = *(const s16x8*)(kr + ((64 + g * 16) ^ swz));
                    f32x4 z = (f32x4){0.f, 0.f, 0.f, 0.f};
                    z = __builtin_amdgcn_mfma_f32_16x16x32_bf16(ka0, qf0, z, 0, 0, 0);
                    st[kf] = __builtin_amdgcn_mfma_f32_16x16x32_bf16(ka1, qf1, z, 0, 0, 0);
                }

                if (t == my_tmax) {
#pragma unroll
                    for (int kf = 0; kf < 4; ++kf) {
#pragma unroll
                        for (int r = 0; r < 4; ++r) {
                            int k = (t << 6) + kf * 16 + 4 * g + r;
                            if (k > q) st[kf][r] = -1e30f;
                        }
                    }
                }

                float pmax = st[0][0];
#pragma unroll
                for (int kf = 0; kf < 4; ++kf) {
#pragma unroll
                    for (int r = 0; r < 4; ++r) pmax = fmaxf(pmax, st[kf][r]);
                }
                pmax = fmaxf(pmax, __shfl_xor(pmax, 16, 64));
                pmax = fmaxf(pmax, __shfl_xor(pmax, 32, 64));
                float mnew = fmaxf(m, pmax);
                float sf = __expf(m - mnew);
                m = mnew;

                float psum = 0.f;
                ushort pb[4][4];
#pragma unroll
                for (int kf = 0; kf < 4; ++kf) {
#pragma unroll
                    for (int r = 0; r < 4; ++r) {
                        float pv = __expf(st[kf][r] - mnew);
                        psum += pv;
                        pb[kf][r] = f2bf(pv);
                    }
                }
                lsum = lsum * sf + psum;
#pragma unroll
                for (int i2 = 0; i2 < 4; ++i2) {
                    o[i2][0] *= sf; o[i2][1] *= sf; o[i2][2] *= sf; o[i2][3] *= sf;
                }

                unsigned pw[4][2];
#pragma unroll
                for (int kf = 0; kf < 4; ++kf) {
                    pw[kf][0] = (unsigned)pb[kf][0] | ((unsigned)pb[kf][1] << 16);
                    pw[kf][1] = (unsigned)pb[kf][2] | ((unsigned)pb[kf][3] << 16);
                }
#pragma unroll
                for (int ks = 0; ks < 2; ++ks) {
                    s16x8 pf = mk8(pw[2 * ks][0], pw[2 * ks][1], pw[2 * ks + 1][0], pw[2 * ks + 1][1]);
#pragma unroll
                    for (int hf = 0; hf < 4; ++hf) {
                        const char* vr = Vb + (hf * 16 + l15) * 128;
                        uint2 lo = *(const uint2*)(vr + ((ks * 64 + g * 8) ^ swz));
                        uint2 hi = *(const uint2*)(vr + ((ks * 64 + 32 + g * 8) ^ swz));
                        o[hf] = __builtin_amdgcn_mfma_f32_16x16x32_bf16(
                            mk8(lo.x, lo.y, hi.x, hi.y), pf, o[hf], 0, 0, 0);
                    }
                }
            }
            __builtin_amdgcn_sched_barrier(0);
            asm volatile("s_waitcnt vmcnt(0)" ::: "memory");
            __builtin_amdgcn_s_barrier();
            __builtin_amdgcn_sched_barrier(0);
        }
    }
#undef STAGE

    __syncthreads();   // staging done everywhere; reuse smem for transpose

    lsum += __shfl_xor(lsum, 16, 64);
    lsum += __shfl_xor(lsum, 32, 64);

    // transpose O^T (16 q-rows x 64 h) through per-wave LDS region, store coalesced
    float* ot = (float*)(smem + w * 4352);     // 16 x 68 floats
#pragma unroll
    for (int hf = 0; hf < 4; ++hf) {
#pragma unroll
        for (int r = 0; r < 4; ++r)
            ot[l15 * 68 + hf * 16 + 4 * g + r] = o[hf][r];
    }
    int rowq = lane >> 2, quad = lane & 3;
    size_t obase = ((size_t)s * 16384 + b * 4096 + q0w + rowq) * 64 + quad * 16;
#pragma unroll
    for (int j = 0; j < 4; ++j) {
        f32x4 vv = *(const f32x4*)&ot[rowq * 68 + quad * 16 + j * 4];
        *(f32x4*)(po + obase + j * 4) = vv;
    }
    if (lane < 16) {
        pml[(size_t)s * 16384 + b * 4096 + q0w + l15] = make_float2(m, lsum);
    }
}

// ---------------- K3: merge KV-split partials ----------------
__global__ __launch_bounds__(256) void merge(const float* __restrict__ po,
                                             const float2* __restrict__ pml,
                                             float* __restrict__ out) {
    int gt = blockIdx.x * 256 + threadIdx.x;   // 0 .. 262143
    int rowq = gt >> 4;                         // b*4096 + t
    int h4 = (gt & 15) << 2;
    float ms[SPLIT], ls[SPLIT];
    float M = -1e30f;
#pragma unroll
    for (int s2 = 0; s2 < SPLIT; ++s2) {
        float2 ml = pml[(size_t)s2 * 16384 + rowq];
        ms[s2] = ml.x; ls[s2] = ml.y;
        M = fmaxf(M, ml.x);
    }
    float L = 0.f;
    float ww[SPLIT];
#pragma unroll
    for (int s2 = 0; s2 < SPLIT; ++s2) {
        float e = __expf(ms[s2] - M);
        ww[s2] = e;
        L += ls[s2] * e;
    }
    f32x4 acc = (f32x4){0.f, 0.f, 0.f, 0.f};
#pragma unroll
    for (int s2 = 0; s2 < SPLIT; ++s2) {
        f32x4 v = *(const f32x4*)(po + ((size_t)s2 * 16384 + rowq) * 64 + h4);
        acc += v * ww[s2];
    }
    float inv = 1.0f / L;
    *(f32x4*)(out + (size_t)rowq * 64 + h4) = acc * inv;
}

extern "C" void kernel_launch(void* const* d_in, const int* in_sizes, int n_in,
                              void* d_out, int out_size, void* d_ws, size_t ws_size,
                              hipStream_t stream) {
    (void)in_sizes; (void)n_in; (void)out_size; (void)ws_size;
    const float* x  = (const float*)d_in[0];
    const float* Wk = (const float*)d_in[1];
    const float* Wq = (const float*)d_in[2];
    const float* Wv = (const float*)d_in[3];
    float* out = (float*)d_out;

    char* ws = (char*)d_ws;
    ushort* wt = (ushort*)(ws);                          // 384 KB
    ushort* qb = (ushort*)(ws + (1u << 20));             // 2 MB
    ushort* kb = (ushort*)(ws + (3u << 20));             // 2 MB
    ushort* vt = (ushort*)(ws + (5u << 20));             // 2 MB
    float*  po = (float*)(ws + ((size_t)8 << 20));       // 32 MB partial O
    float2* pml = (float2*)(ws + ((size_t)40 << 20));    // 1 MB partial m,l

    prep_w<<<48, 256, 0, stream>>>(Wk, Wq, Wv, wt);
    proj<<<256, 512, 0, stream>>>(x, wt, qb, kb, vt);
    attn<<<1024, 512, 0, stream>>>(qb, kb, vt, po, pml);
    merge<<<1024, 256, 0, stream>>>(po, pml, out);
}

// Round 7
// 139.378 us; speedup vs baseline: 2.1958x; 1.0206x over previous
//
#include <hip/hip_runtime.h>
#include <hip/hip_bf16.h>

typedef __attribute__((ext_vector_type(8))) short s16x8;
typedef __attribute__((ext_vector_type(4))) float f32x4;

#define TSEQ 4096
#define SPLIT 8

static __device__ __forceinline__ ushort f2bf(float f) {
    union { float f; unsigned u; } v; v.f = f;
    unsigned u = v.u;
    unsigned r = (u + 0x7fffu + ((u >> 16) & 1u)) >> 16;
    return (ushort)r;
}

static __device__ __forceinline__ float bf2f(unsigned lo16) {
    union { unsigned u; float f; } v; v.u = lo16 << 16; return v.f;
}

static __device__ __forceinline__ float fexp2(float x) {   // 2^x, raw v_exp_f32
    float r; asm("v_exp_f32 %0, %1" : "=v"(r) : "v"(x)); return r;
}

static __device__ __forceinline__ s16x8 mk8(unsigned a, unsigned b, unsigned c, unsigned d) {
    union { uint4 u; s16x8 v; } x; x.u = make_uint4(a, b, c, d); return x.v;
}

static __device__ __forceinline__ void gload_lds16(const void* g, void* l) {
    __builtin_amdgcn_global_load_lds(
        (const __attribute__((address_space(1))) unsigned int*)g,
        (__attribute__((address_space(3))) unsigned int*)l, 16, 0, 0);
}

// ---------------- K0: weight prep ----------------
// wt[192][1024] bf16: rows 0-63 = Wq^T scaled by 1/(32*ln2) (exp2-domain scores),
// 64-127 = Wk^T, 128-191 = Wv^T
__global__ __launch_bounds__(256) void prep_w(const float* __restrict__ Wk,
                                              const float* __restrict__ Wq,
                                              const float* __restrict__ Wv,
                                              ushort* __restrict__ wt) {
    __shared__ float tile[64][65];
    int bid = blockIdx.x;
    int mi = bid >> 4;               // 0=q, 1=k, 2=v
    int e0 = (bid & 15) << 6;
    const float* src = (mi == 0) ? Wq : (mi == 1) ? Wk : Wv;
    int n = threadIdx.x & 63;
    int quad = threadIdx.x >> 6;
#pragma unroll
    for (int r = 0; r < 16; ++r) {
        int el = r * 4 + quad;
        tile[el][n] = src[(size_t)(e0 + el) * 64 + n];
    }
    __syncthreads();
    float scale = (mi == 0) ? 0.045084224f : 1.0f;   // 1/(32*ln2)
    int ecol = threadIdx.x & 63;
#pragma unroll
    for (int r = 0; r < 16; ++r) {
        int nl = r * 4 + quad;
        wt[(size_t)(mi * 64 + nl) * 1024 + e0 + ecol] = f2bf(tile[ecol][nl] * scale);
    }
}

// ---------------- K1: QKV projection, 3-deep DMA pipeline ----------------
__global__ __launch_bounds__(512) void proj(const float* __restrict__ x,
                                            const ushort* __restrict__ wt,
                                            ushort* __restrict__ qb,
                                            ushort* __restrict__ kb,
                                            ushort* __restrict__ vt) {
    __shared__ char smem[3 * 40960];     // per buf: [A 16K f32][B 24K bf16]
    int tid = threadIdx.x;
    int lane = tid & 63, w = tid >> 6;
    int l15 = lane & 15, g = lane >> 4;
    int mh = w >> 2, nq = w & 3;
    size_t m0 = (size_t)blockIdx.x * 64;

    int rA = tid >> 4, sA = tid & 15;
    const float* xsrc = x + (m0 + rA) * 1024 + ((sA ^ (rA & 15)) << 2);
    int rB = tid >> 3, sB = tid & 7;
    const ushort* wsrc = wt + (size_t)rB * 1024 + ((sB ^ (rB & 7)) << 3);

    f32x4 acc[2][3];
#pragma unroll
    for (int mi = 0; mi < 2; ++mi)
#pragma unroll
        for (int j = 0; j < 3; ++j) acc[mi][j] = (f32x4){0.f, 0.f, 0.f, 0.f};

#define PSTAGE(bufsel, it) do {                                        \
        size_t k0_ = (size_t)(it) << 6;                                \
        char* bb_ = smem + (bufsel) * 40960;                           \
        gload_lds16(xsrc + k0_, bb_ + tid * 16);                       \
        gload_lds16(xsrc + 32 * 1024 + k0_, bb_ + 8192 + tid * 16);    \
        gload_lds16(wsrc + k0_, bb_ + 16384 + tid * 16);               \
        gload_lds16(wsrc + 64 * 1024 + k0_, bb_ + 24576 + tid * 16);   \
        gload_lds16(wsrc + 128 * 1024 + k0_, bb_ + 32768 + tid * 16);  \
    } while (0)

    PSTAGE(0, 0);
    PSTAGE(1, 1);
    for (int i = 0; i < 16; ++i) {
        int cur = i % 3;
        __builtin_amdgcn_sched_barrier(0);
        if (i < 15) asm volatile("s_waitcnt vmcnt(5)" ::: "memory");
        else        asm volatile("s_waitcnt vmcnt(0)" ::: "memory");
        __builtin_amdgcn_s_barrier();
        __builtin_amdgcn_sched_barrier(0);
        if (i + 2 < 16) PSTAGE((i + 2) % 3, i + 2);

        const char* Ab = smem + cur * 40960;
        const char* Bb = Ab + 16384;
#pragma unroll
        for (int ks = 0; ks < 2; ++ks) {
            s16x8 a[2];
#pragma unroll
            for (int mi = 0; mi < 2; ++mi) {
                int row = mh * 32 + mi * 16 + l15;
                int s0 = ks * 8 + g * 2;
                f32x4 xa = *(const f32x4*)(Ab + row * 256 + ((s0 ^ l15) << 4));
                f32x4 xb2 = *(const f32x4*)(Ab + row * 256 + (((s0 + 1) ^ l15) << 4));
#pragma unroll
                for (int q2 = 0; q2 < 4; ++q2) {
                    a[mi][q2] = (short)f2bf(xa[q2]);
                    a[mi][q2 + 4] = (short)f2bf(xb2[q2]);
                }
            }
#pragma unroll
            for (int j = 0; j < 3; ++j) {
                int n = nq * 48 + j * 16 + l15;
                s16x8 bf = *(const s16x8*)(Bb + n * 128 + (((ks * 4 + g) ^ (l15 & 7)) << 4));
#pragma unroll
                for (int mi = 0; mi < 2; ++mi)
                    acc[mi][j] = __builtin_amdgcn_mfma_f32_16x16x32_bf16(a[mi], bf, acc[mi][j], 0, 0, 0);
            }
        }
    }
#undef PSTAGE

    size_t bb = m0 >> 12;
    size_t t00 = m0 & 4095;
#pragma unroll
    for (int mi = 0; mi < 2; ++mi) {
        size_t Mb = m0 + mh * 32 + mi * 16 + 4 * g;
#pragma unroll
        for (int j = 0; j < 3; ++j) {
            int nf = nq * 3 + j;
            int n = nf * 16 + l15;
            if (nf < 4) {
#pragma unroll
                for (int r = 0; r < 4; ++r)
                    qb[(Mb + r) * 64 + n] = f2bf(acc[mi][j][r]);
            } else if (nf < 8) {
#pragma unroll
                for (int r = 0; r < 4; ++r)
                    kb[(Mb + r) * 64 + (n - 64)] = f2bf(acc[mi][j][r]);
            } else {
                int h = n - 128;
                size_t tloc = t00 + mh * 32 + mi * 16 + 4 * g;
                unsigned w0 = (unsigned)f2bf(acc[mi][j][0]) | ((unsigned)f2bf(acc[mi][j][1]) << 16);
                unsigned w1 = (unsigned)f2bf(acc[mi][j][2]) | ((unsigned)f2bf(acc[mi][j][3]) << 16);
                *(uint2*)(vt + (bb * 64 + h) * TSEQ + tloc) = make_uint2(w0, w1);
            }
        }
    }
}

// ---------------- K2: flash attention, 3-ring KV pipeline, exp2 softmax ----------------
__global__ __launch_bounds__(512) void attn(const ushort* __restrict__ qb,
                                            const ushort* __restrict__ kb,
                                            const ushort* __restrict__ vt,
                                            ushort* __restrict__ po,
                                            float2* __restrict__ pml) {
    __shared__ char smem[49152];   // [K x3 8K][V x3 8K]; reused for O-transpose
    int tid = threadIdx.x;
    int lane = tid & 63, w = tid >> 6;
    int l15 = lane & 15, g = lane >> 4;
    int bid = blockIdx.x;
    int s = bid & 7;
    int b = (bid >> 3) & 3;
    int idx = bid >> 5;
    int p = (idx < 16) ? (31 - idx) : (idx - 16);
    int q0w = p * 128 + w * 16;
    int q = q0w + l15;
    int my_tmax = q0w >> 6;
    int nkvb = 2 * p + 2;
    int cnt = (s < nkvb) ? ((nkvb + 7 - s) >> 3) : 0;

    int row = tid >> 3;
    int kswz = (((tid & 7) ^ (row & 7)) << 3);

    const ushort* qbase = qb + ((size_t)b * TSEQ + q) * 64;
    s16x8 qf0 = *(const s16x8*)(qbase + g * 8);
    s16x8 qf1 = *(const s16x8*)(qbase + 32 + g * 8);

    f32x4 o[4];
#pragma unroll
    for (int i = 0; i < 4; ++i) o[i] = (f32x4){0.f, 0.f, 0.f, 0.f};
    float m = -1e30f, lsum = 0.f;

#define STAGE(bufsel, tt) do {                                                         \
        const ushort* ksrc_ = kb + ((size_t)b * TSEQ + (size_t)(tt) * 64 + row) * 64 + kswz; \
        gload_lds16(ksrc_, smem + (bufsel) * 8192 + tid * 16);                         \
        const ushort* vsrc_ = vt + ((size_t)b * 64 + row) * TSEQ + (size_t)(tt) * 64 + kswz; \
        gload_lds16(vsrc_, smem + 24576 + (bufsel) * 8192 + tid * 16);                 \
    } while (0)

    if (cnt > 0) {
        STAGE(0, s);
        if (cnt > 1) STAGE(1, s + 8);
        for (int i = 0; i < cnt; ++i) {
            int t = s + (i << 3);
            int cur = i % 3;
            __builtin_amdgcn_sched_barrier(0);
            if (i + 1 < cnt) asm volatile("s_waitcnt vmcnt(2)" ::: "memory");
            else             asm volatile("s_waitcnt vmcnt(0)" ::: "memory");
            __builtin_amdgcn_s_barrier();
            __builtin_amdgcn_sched_barrier(0);
            if (i + 2 < cnt) STAGE((i + 2) % 3, t + 16);

            if (t <= my_tmax) {
                const char* Kb = smem + cur * 8192;
                const char* Vb = smem + 24576 + cur * 8192;
                int swz = (l15 & 7) << 4;

                f32x4 st[4];
#pragma unroll
                for (int kf = 0; kf < 4; ++kf) {
                    const char* kr = Kb + (kf * 16 + l15) * 128;
                    s16x8 ka0 = *(const s16x8*)(kr + ((g * 16) ^ swz));
                    s16x8 ka1 = *(const s16x8*)(kr + ((64 + g * 16) ^ swz));
                    f32x4 z = (f32x4){0.f, 0.f, 0.f, 0.f};
                    z = __builtin_amdgcn_mfma_f32_16x16x32_bf16(ka0, qf0, z, 0, 0, 0);
                    st[kf] = __builtin_amdgcn_mfma_f32_16x16x32_bf16(ka1, qf1, z, 0, 0, 0);
                }

                if (t == my_tmax) {
#pragma unroll
                    for (int kf = 0; kf < 4; ++kf) {
#pragma unroll
                        for (int r = 0; r < 4; ++r) {
                            int k = (t << 6) + kf * 16 + 4 * g + r;
                            if (k > q) st[kf][r] = -1e30f;
                        }
                    }
                }

                float pmax = st[0][0];
#pragma unroll
                for (int kf = 0; kf < 4; ++kf) {
#pragma unroll
                    for (int r = 0; r < 4; ++r) pmax = fmaxf(pmax, st[kf][r]);
                }
                pmax = fmaxf(pmax, __shfl_xor(pmax, 16, 64));
                pmax = fmaxf(pmax, __shfl_xor(pmax, 32, 64));

                // defer-max: skip rescale when growth <= 8 (log2-domain)
                if (!__all(pmax - m <= 8.0f)) {
                    float mnew = fmaxf(m, pmax);
                    float sf = fexp2(m - mnew);
                    m = mnew;
                    lsum *= sf;
#pragma unroll
                    for (int i2 = 0; i2 < 4; ++i2) {
                        o[i2][0] *= sf; o[i2][1] *= sf; o[i2][2] *= sf; o[i2][3] *= sf;
                    }
                }

                float psum = 0.f;
                ushort pb[4][4];
#pragma unroll
                for (int kf = 0; kf < 4; ++kf) {
#pragma unroll
                    for (int r = 0; r < 4; ++r) {
                        float pv = fexp2(st[kf][r] - m);
                        psum += pv;
                        pb[kf][r] = f2bf(pv);
                    }
                }
                lsum += psum;

                unsigned pw[4][2];
#pragma unroll
                for (int kf = 0; kf < 4; ++kf) {
                    pw[kf][0] = (unsigned)pb[kf][0] | ((unsigned)pb[kf][1] << 16);
                    pw[kf][1] = (unsigned)pb[kf][2] | ((unsigned)pb[kf][3] << 16);
                }
#pragma unroll
                for (int ks = 0; ks < 2; ++ks) {
                    s16x8 pf = mk8(pw[2 * ks][0], pw[2 * ks][1], pw[2 * ks + 1][0], pw[2 * ks + 1][1]);
#pragma unroll
                    for (int hf = 0; hf < 4; ++hf) {
                        const char* vr = Vb + (hf * 16 + l15) * 128;
                        uint2 lo = *(const uint2*)(vr + ((ks * 64 + g * 8) ^ swz));
                        uint2 hi = *(const uint2*)(vr + ((ks * 64 + 32 + g * 8) ^ swz));
                        o[hf] = __builtin_amdgcn_mfma_f32_16x16x32_bf16(
                            mk8(lo.x, lo.y, hi.x, hi.y), pf, o[hf], 0, 0, 0);
                    }
                }
            }
        }
    }
#undef STAGE

    __syncthreads();   // all staging/compute done; reuse smem for O transpose

    lsum += __shfl_xor(lsum, 16, 64);
    lsum += __shfl_xor(lsum, 32, 64);

    float* ot = (float*)(smem + w * 4352);     // 16 x 68 floats
#pragma unroll
    for (int hf = 0; hf < 4; ++hf) {
#pragma unroll
        for (int r = 0; r < 4; ++r)
            ot[l15 * 68 + hf * 16 + 4 * g + r] = o[hf][r];
    }
    int rowq = lane >> 2, quad = lane & 3;
    const float* src = &ot[rowq * 68 + quad * 16];
    unsigned pk[8];
#pragma unroll
    for (int j = 0; j < 8; ++j)
        pk[j] = (unsigned)f2bf(src[2 * j]) | ((unsigned)f2bf(src[2 * j + 1]) << 16);
    ushort* dst = po + ((size_t)s * 16384 + b * 4096 + q0w + rowq) * 64 + quad * 16;
    *(uint4*)dst = make_uint4(pk[0], pk[1], pk[2], pk[3]);
    *(uint4*)(dst + 8) = make_uint4(pk[4], pk[5], pk[6], pk[7]);

    if (lane < 16) {
        pml[(size_t)s * 16384 + b * 4096 + q0w + l15] = make_float2(m, lsum);
    }
}

// ---------------- K3: merge KV-split partials (bf16 po, exp2 weights) ----------------
__global__ __launch_bounds__(256) void merge(const ushort* __restrict__ po,
                                             const float2* __restrict__ pml,
                                             float* __restrict__ out) {
    int gt = blockIdx.x * 256 + threadIdx.x;
    int rowq = gt >> 4;
    int h4 = (gt & 15) << 2;
    float ms[SPLIT], ls[SPLIT];
    float M = -1e30f;
#pragma unroll
    for (int s2 = 0; s2 < SPLIT; ++s2) {
        float2 ml = pml[(size_t)s2 * 16384 + rowq];
        ms[s2] = ml.x; ls[s2] = ml.y;
        M = fmaxf(M, ml.x);
    }
    float L = 0.f;
    float ww[SPLIT];
#pragma unroll
    for (int s2 = 0; s2 < SPLIT; ++s2) {
        float e = fexp2(ms[s2] - M);
        ww[s2] = e;
        L += ls[s2] * e;
    }
    f32x4 acc = (f32x4){0.f, 0.f, 0.f, 0.f};
#pragma unroll
    for (int s2 = 0; s2 < SPLIT; ++s2) {
        uint2 pv = *(const uint2*)(po + ((size_t)s2 * 16384 + rowq) * 64 + h4);
        float wgt = ww[s2];
        acc[0] += wgt * bf2f(pv.x & 0xffffu);
        acc[1] += wgt * bf2f(pv.x >> 16);
        acc[2] += wgt * bf2f(pv.y & 0xffffu);
        acc[3] += wgt * bf2f(pv.y >> 16);
    }
    float inv = 1.0f / L;
    *(f32x4*)(out + (size_t)rowq * 64 + h4) = acc * inv;
}

extern "C" void kernel_launch(void* const* d_in, const int* in_sizes, int n_in,
                              void* d_out, int out_size, void* d_ws, size_t ws_size,
                              hipStream_t stream) {
    (void)in_sizes; (void)n_in; (void)out_size; (void)ws_size;
    const float* x  = (const float*)d_in[0];
    const float* Wk = (const float*)d_in[1];
    const float* Wq = (const float*)d_in[2];
    const float* Wv = (const float*)d_in[3];
    float* out = (float*)d_out;

    char* ws = (char*)d_ws;
    ushort* wt = (ushort*)(ws);                          // 384 KB
    ushort* qb = (ushort*)(ws + (1u << 20));             // 2 MB
    ushort* kb = (ushort*)(ws + (3u << 20));             // 2 MB
    ushort* vt = (ushort*)(ws + (5u << 20));             // 2 MB
    ushort* po = (ushort*)(ws + ((size_t)8 << 20));      // 16 MB partial O (bf16)
    float2* pml = (float2*)(ws + ((size_t)26 << 20));    // 1 MB partial m,l

    prep_w<<<48, 256, 0, stream>>>(Wk, Wq, Wv, wt);
    proj<<<256, 512, 0, stream>>>(x, wt, qb, kb, vt);
    attn<<<1024, 512, 0, stream>>>(qb, kb, vt, po, pml);
    merge<<<1024, 256, 0, stream>>>(po, pml, out);
}

// Round 9
// 134.600 us; speedup vs baseline: 2.2737x; 1.0355x over previous
//
#include <hip/hip_runtime.h>
#include <hip/hip_bf16.h>

typedef __attribute__((ext_vector_type(8))) short s16x8;
typedef __attribute__((ext_vector_type(4))) float f32x4;

#define TSEQ 4096
#define SPLIT 4

static __device__ __forceinline__ ushort f2bf(float f) {
    union { float f; unsigned u; } v; v.f = f;
    unsigned u = v.u;
    unsigned r = (u + 0x7fffu + ((u >> 16) & 1u)) >> 16;
    return (ushort)r;
}

static __device__ __forceinline__ float bf2f(unsigned lo16) {
    union { unsigned u; float f; } v; v.u = lo16 << 16; return v.f;
}

static __device__ __forceinline__ float fexp2(float x) {   // 2^x, raw v_exp_f32
    float r; asm("v_exp_f32 %0, %1" : "=v"(r) : "v"(x)); return r;
}

static __device__ __forceinline__ s16x8 mk8(unsigned a, unsigned b, unsigned c, unsigned d) {
    union { uint4 u; s16x8 v; } x; x.u = make_uint4(a, b, c, d); return x.v;
}

static __device__ __forceinline__ void gload_lds16(const void* g, void* l) {
    __builtin_amdgcn_global_load_lds(
        (const __attribute__((address_space(1))) unsigned int*)g,
        (__attribute__((address_space(3))) unsigned int*)l, 16, 0, 0);
}

// ---------------- K0: weight prep ----------------
// wt[192][1024] bf16: rows 0-63 = Wq^T scaled by 1/(32*ln2) (exp2-domain scores),
// 64-127 = Wk^T, 128-191 = Wv^T
__global__ __launch_bounds__(256) void prep_w(const float* __restrict__ Wk,
                                              const float* __restrict__ Wq,
                                              const float* __restrict__ Wv,
                                              ushort* __restrict__ wt) {
    __shared__ float tile[64][65];
    int bid = blockIdx.x;
    int mi = bid >> 4;               // 0=q, 1=k, 2=v
    int e0 = (bid & 15) << 6;
    const float* src = (mi == 0) ? Wq : (mi == 1) ? Wk : Wv;
    int n = threadIdx.x & 63;
    int quad = threadIdx.x >> 6;
#pragma unroll
    for (int r = 0; r < 16; ++r) {
        int el = r * 4 + quad;
        tile[el][n] = src[(size_t)(e0 + el) * 64 + n];
    }
    __syncthreads();
    float scale = (mi == 0) ? 0.045084224f : 1.0f;   // 1/(32*ln2)
    int ecol = threadIdx.x & 63;
#pragma unroll
    for (int r = 0; r < 16; ++r) {
        int nl = r * 4 + quad;
        wt[(size_t)(mi * 64 + nl) * 1024 + e0 + ecol] = f2bf(tile[ecol][nl] * scale);
    }
}

// ---------------- K1: QKV projection, 3-deep DMA pipeline ----------------
__global__ __launch_bounds__(512) void proj(const float* __restrict__ x,
                                            const ushort* __restrict__ wt,
                                            ushort* __restrict__ qb,
                                            ushort* __restrict__ kb,
                                            ushort* __restrict__ vt) {
    __shared__ char smem[3 * 40960];     // per buf: [A 16K f32][B 24K bf16]
    int tid = threadIdx.x;
    int lane = tid & 63, w = tid >> 6;
    int l15 = lane & 15, g = lane >> 4;
    int mh = w >> 2, nq = w & 3;
    size_t m0 = (size_t)blockIdx.x * 64;

    int rA = tid >> 4, sA = tid & 15;
    const float* xsrc = x + (m0 + rA) * 1024 + ((sA ^ (rA & 15)) << 2);
    int rB = tid >> 3, sB = tid & 7;
    const ushort* wsrc = wt + (size_t)rB * 1024 + ((sB ^ (rB & 7)) << 3);

    f32x4 acc[2][3];
#pragma unroll
    for (int mi = 0; mi < 2; ++mi)
#pragma unroll
        for (int j = 0; j < 3; ++j) acc[mi][j] = (f32x4){0.f, 0.f, 0.f, 0.f};

#define PSTAGE(bufsel, it) do {                                        \
        size_t k0_ = (size_t)(it) << 6;                                \
        char* bb_ = smem + (bufsel) * 40960;                           \
        gload_lds16(xsrc + k0_, bb_ + tid * 16);                       \
        gload_lds16(xsrc + 32 * 1024 + k0_, bb_ + 8192 + tid * 16);    \
        gload_lds16(wsrc + k0_, bb_ + 16384 + tid * 16);               \
        gload_lds16(wsrc + 64 * 1024 + k0_, bb_ + 24576 + tid * 16);   \
        gload_lds16(wsrc + 128 * 1024 + k0_, bb_ + 32768 + tid * 16);  \
    } while (0)

    PSTAGE(0, 0);
    PSTAGE(1, 1);
    for (int i = 0; i < 16; ++i) {
        int cur = i % 3;
        __builtin_amdgcn_sched_barrier(0);
        if (i < 15) asm volatile("s_waitcnt vmcnt(5)" ::: "memory");
        else        asm volatile("s_waitcnt vmcnt(0)" ::: "memory");
        __builtin_amdgcn_s_barrier();
        __builtin_amdgcn_sched_barrier(0);
        if (i + 2 < 16) PSTAGE((i + 2) % 3, i + 2);

        const char* Ab = smem + cur * 40960;
        const char* Bb = Ab + 16384;
#pragma unroll
        for (int ks = 0; ks < 2; ++ks) {
            s16x8 a[2];
#pragma unroll
            for (int mi = 0; mi < 2; ++mi) {
                int row = mh * 32 + mi * 16 + l15;
                int s0 = ks * 8 + g * 2;
                f32x4 xa = *(const f32x4*)(Ab + row * 256 + ((s0 ^ l15) << 4));
                f32x4 xb2 = *(const f32x4*)(Ab + row * 256 + (((s0 + 1) ^ l15) << 4));
#pragma unroll
                for (int q2 = 0; q2 < 4; ++q2) {
                    a[mi][q2] = (short)f2bf(xa[q2]);
                    a[mi][q2 + 4] = (short)f2bf(xb2[q2]);
                }
            }
#pragma unroll
            for (int j = 0; j < 3; ++j) {
                int n = nq * 48 + j * 16 + l15;
                s16x8 bf = *(const s16x8*)(Bb + n * 128 + (((ks * 4 + g) ^ (l15 & 7)) << 4));
#pragma unroll
                for (int mi = 0; mi < 2; ++mi)
                    acc[mi][j] = __builtin_amdgcn_mfma_f32_16x16x32_bf16(a[mi], bf, acc[mi][j], 0, 0, 0);
            }
        }
    }
#undef PSTAGE

    size_t bb = m0 >> 12;
    size_t t00 = m0 & 4095;
#pragma unroll
    for (int mi = 0; mi < 2; ++mi) {
        size_t Mb = m0 + mh * 32 + mi * 16 + 4 * g;
#pragma unroll
        for (int j = 0; j < 3; ++j) {
            int nf = nq * 3 + j;
            int n = nf * 16 + l15;
            if (nf < 4) {
#pragma unroll
                for (int r = 0; r < 4; ++r)
                    qb[(Mb + r) * 64 + n] = f2bf(acc[mi][j][r]);
            } else if (nf < 8) {
#pragma unroll
                for (int r = 0; r < 4; ++r)
                    kb[(Mb + r) * 64 + (n - 64)] = f2bf(acc[mi][j][r]);
            } else {
                int h = n - 128;
                size_t tloc = t00 + mh * 32 + mi * 16 + 4 * g;
                unsigned w0 = (unsigned)f2bf(acc[mi][j][0]) | ((unsigned)f2bf(acc[mi][j][1]) << 16);
                unsigned w1 = (unsigned)f2bf(acc[mi][j][2]) | ((unsigned)f2bf(acc[mi][j][3]) << 16);
                *(uint2*)(vt + (bb * 64 + h) * TSEQ + tloc) = make_uint2(w0, w1);
            }
        }
    }
}

// ---------------- K2: flash attention, KVBLK=128, 2-ring counted pipeline ----------------
// Block = (b, 128-row q-panel p, kv-slice s of 4). 8 waves x 16 q-rows.
// Tile = 128 k-rows: K[128][64] + V^T[64][128] staged via global_load_lds
// (pre-swizzled source), 2-buffer ring, counted vmcnt(4), 2 barriers/iter.
// All waves compute every tile; mask only on diagonal tile t==p.
__global__ __launch_bounds__(512, 2) void attn(const ushort* __restrict__ qb,
                                               const ushort* __restrict__ kb,
                                               const ushort* __restrict__ vt,
                                               ushort* __restrict__ po,
                                               float2* __restrict__ pml) {
    __shared__ char smem[65536];   // [K buf0 16K][K buf1 16K][V buf0 16K][V buf1 16K]
    char* smK = smem;
    char* smV = smem + 32768;
    int tid = threadIdx.x;
    int lane = tid & 63, w = tid >> 6;
    int l15 = lane & 15, g = lane >> 4;
    int bid = blockIdx.x;
    int s = bid & 3;
    int b = (bid >> 2) & 3;
    int idx = bid >> 4;                         // 0..31
    int p = (idx < 16) ? (31 - idx) : (idx - 16);   // heavy-first
    int q0w = p * 128 + w * 16;
    int nkvt = p + 1;                            // 128-wide tiles
    int cnt = (s < nkvt) ? ((nkvt - s + 3) >> 2) : 0;

    // staging geometry (pre-swizzled global source, linear LDS dest)
    int rK = tid >> 3;                           // K row 0..63 (+64 second pass)
    int kxs = (((tid & 7) ^ (rK & 7)) << 3);     // ushort offset
    int hV = tid >> 4;                           // V row 0..31 (+32 second pass)
    int vxs = (((tid & 15) ^ (hV & 15)) << 3);

    const ushort* qbase = qb + ((size_t)b * TSEQ + q0w + l15) * 64;
    s16x8 qf0 = *(const s16x8*)(qbase + g * 8);
    s16x8 qf1 = *(const s16x8*)(qbase + 32 + g * 8);

    f32x4 o[4];
#pragma unroll
    for (int i = 0; i < 4; ++i) o[i] = (f32x4){0.f, 0.f, 0.f, 0.f};
    float m = -1e30f, lsum = 0.f;

#define STAGE(bufsel, tt) do {                                                          \
        const ushort* kA_ = kb + ((size_t)b * TSEQ + (size_t)(tt) * 128 + rK) * 64 + kxs; \
        gload_lds16(kA_, smK + (bufsel) * 16384 + tid * 16);                            \
        gload_lds16(kA_ + 64 * 64, smK + (bufsel) * 16384 + 8192 + tid * 16);           \
        const ushort* vA_ = vt + ((size_t)b * 64 + hV) * TSEQ + (size_t)(tt) * 128 + vxs; \
        gload_lds16(vA_, smV + (bufsel) * 16384 + tid * 16);                            \
        gload_lds16(vA_ + 32 * TSEQ, smV + (bufsel) * 16384 + 8192 + tid * 16);         \
    } while (0)

    if (cnt > 0) {
        STAGE(0, s);
        if (cnt > 1) STAGE(1, s + 4);
        for (int i = 0; i < cnt; ++i) {
            int t = s + (i << 2);
            int cur = i & 1;
            __builtin_amdgcn_sched_barrier(0);
            if (i + 1 < cnt) asm volatile("s_waitcnt vmcnt(4)" ::: "memory");
            else             asm volatile("s_waitcnt vmcnt(0)" ::: "memory");
            __builtin_amdgcn_s_barrier();
            __builtin_amdgcn_sched_barrier(0);

            const char* Kb = smK + cur * 16384;
            const char* Vb = smV + cur * 16384;
            int swzk = (l15 & 7) << 4;

            // QK^T: 16 MFMA, st[kf] col q=l15, row k_local = kf*16 + 4g + r
            f32x4 st[8];
#pragma unroll
            for (int kf = 0; kf < 8; ++kf) {
                const char* kr = Kb + (kf * 16 + l15) * 128;
                s16x8 ka0 = *(const s16x8*)(kr + ((g << 4) ^ swzk));
                s16x8 ka1 = *(const s16x8*)(kr + (((4 + g) << 4) ^ swzk));
                f32x4 z = (f32x4){0.f, 0.f, 0.f, 0.f};
                z = __builtin_amdgcn_mfma_f32_16x16x32_bf16(ka0, qf0, z, 0, 0, 0);
                st[kf] = __builtin_amdgcn_mfma_f32_16x16x32_bf16(ka1, qf1, z, 0, 0, 0);
            }

            if (t == p) {        // diagonal tile: mask k_local > q_local
                int ql = w * 16 + l15;
#pragma unroll
                for (int kf = 0; kf < 8; ++kf) {
#pragma unroll
                    for (int r = 0; r < 4; ++r) {
                        if (kf * 16 + 4 * g + r > ql) st[kf][r] = -1e30f;
                    }
                }
            }

            float pmax = st[0][0];
#pragma unroll
            for (int kf = 0; kf < 8; ++kf) {
#pragma unroll
                for (int r = 0; r < 4; ++r) pmax = fmaxf(pmax, st[kf][r]);
            }
            pmax = fmaxf(pmax, __shfl_xor(pmax, 16, 64));
            pmax = fmaxf(pmax, __shfl_xor(pmax, 32, 64));

            if (!__all(pmax - m <= 8.0f)) {      // defer-max (log2 domain)
                float mnew = fmaxf(m, pmax);
                float sf = fexp2(m - mnew);
                m = mnew;
                lsum *= sf;
#pragma unroll
                for (int i2 = 0; i2 < 4; ++i2) {
                    o[i2][0] *= sf; o[i2][1] *= sf; o[i2][2] *= sf; o[i2][3] *= sf;
                }
            }

            float psum = 0.f;
            unsigned pw[8][2];
#pragma unroll
            for (int kf = 0; kf < 8; ++kf) {
                float p0 = fexp2(st[kf][0] - m);
                float p1 = fexp2(st[kf][1] - m);
                float p2 = fexp2(st[kf][2] - m);
                float p3 = fexp2(st[kf][3] - m);
                psum += (p0 + p1) + (p2 + p3);
                pw[kf][0] = (unsigned)f2bf(p0) | ((unsigned)f2bf(p1) << 16);
                pw[kf][1] = (unsigned)f2bf(p2) | ((unsigned)f2bf(p3) << 16);
            }
            lsum += psum;

            // PV: 16 MFMA; slot bijection pi(i) = (2ks + (i>>2))*16 + 4g + (i&3)
#pragma unroll
            for (int ks = 0; ks < 4; ++ks) {
                s16x8 pf = mk8(pw[2 * ks][0], pw[2 * ks][1], pw[2 * ks + 1][0], pw[2 * ks + 1][1]);
#pragma unroll
                for (int hf = 0; hf < 4; ++hf) {
                    const char* vr = Vb + (hf * 16 + l15) * 256;
                    int j0 = ks * 4 + (g >> 1), o0 = (g & 1) * 8;
                    uint2 lo = *(const uint2*)(vr + ((j0 ^ l15) << 4) + o0);
                    uint2 hi = *(const uint2*)(vr + (((j0 + 2) ^ l15) << 4) + o0);
                    o[hf] = __builtin_amdgcn_mfma_f32_16x16x32_bf16(
                        mk8(lo.x, lo.y, hi.x, hi.y), pf, o[hf], 0, 0, 0);
                }
            }

            __builtin_amdgcn_sched_barrier(0);
            __builtin_amdgcn_s_barrier();        // all waves done reading buf cur
            __builtin_amdgcn_sched_barrier(0);
            if (i + 2 < cnt) STAGE(cur, t + 8);  // refill the buffer just consumed
        }
    }
#undef STAGE

    __syncthreads();   // full drain; reuse smem for O transpose

    lsum += __shfl_xor(lsum, 16, 64);
    lsum += __shfl_xor(lsum, 32, 64);

    float* ot = (float*)(smem + w * 4352);     // 16 x 68 floats per wave
#pragma unroll
    for (int hf = 0; hf < 4; ++hf) {
#pragma unroll
        for (int r = 0; r < 4; ++r)
            ot[l15 * 68 + hf * 16 + 4 * g + r] = o[hf][r];
    }
    int rowq = lane >> 2, quad = lane & 3;
    const float* srcp = &ot[rowq * 68 + quad * 16];
    unsigned pk[8];
#pragma unroll
    for (int j = 0; j < 8; ++j)
        pk[j] = (unsigned)f2bf(srcp[2 * j]) | ((unsigned)f2bf(srcp[2 * j + 1]) << 16);
    ushort* dst = po + ((size_t)s * 16384 + b * 4096 + q0w + rowq) * 64 + quad * 16;
    *(uint4*)dst = make_uint4(pk[0], pk[1], pk[2], pk[3]);
    *(uint4*)(dst + 8) = make_uint4(pk[4], pk[5], pk[6], pk[7]);

    if (lane < 16) {
        pml[(size_t)s * 16384 + b * 4096 + q0w + l15] = make_float2(m, lsum);
    }
}

// ---------------- K3: merge KV-split partials (bf16 po, exp2 weights) ----------------
__global__ __launch_bounds__(256) void merge(const ushort* __restrict__ po,
                                             const float2* __restrict__ pml,
                                             float* __restrict__ out) {
    int gt = blockIdx.x * 256 + threadIdx.x;
    int rowq = gt >> 4;
    int h4 = (gt & 15) << 2;
    float ms[SPLIT], ls[SPLIT];
    float M = -1e30f;
#pragma unroll
    for (int s2 = 0; s2 < SPLIT; ++s2) {
        float2 ml = pml[(size_t)s2 * 16384 + rowq];
        ms[s2] = ml.x; ls[s2] = ml.y;
        M = fmaxf(M, ml.x);
    }
    float L = 0.f;
    float ww[SPLIT];
#pragma unroll
    for (int s2 = 0; s2 < SPLIT; ++s2) {
        float e = fexp2(ms[s2] - M);
        ww[s2] = e;
        L += ls[s2] * e;
    }
    f32x4 acc = (f32x4){0.f, 0.f, 0.f, 0.f};
#pragma unroll
    for (int s2 = 0; s2 < SPLIT; ++s2) {
        uint2 pv = *(const uint2*)(po + ((size_t)s2 * 16384 + rowq) * 64 + h4);
        float wgt = ww[s2];
        acc[0] += wgt * bf2f(pv.x & 0xffffu);
        acc[1] += wgt * bf2f(pv.x >> 16);
        acc[2] += wgt * bf2f(pv.y & 0xffffu);
        acc[3] += wgt * bf2f(pv.y >> 16);
    }
    float inv = 1.0f / L;
    *(f32x4*)(out + (size_t)rowq * 64 + h4) = acc * inv;
}

extern "C" void kernel_launch(void* const* d_in, const int* in_sizes, int n_in,
                              void* d_out, int out_size, void* d_ws, size_t ws_size,
                              hipStream_t stream) {
    (void)in_sizes; (void)n_in; (void)out_size; (void)ws_size;
    const float* x  = (const float*)d_in[0];
    const float* Wk = (const float*)d_in[1];
    const float* Wq = (const float*)d_in[2];
    const float* Wv = (const float*)d_in[3];
    float* out = (float*)d_out;

    char* ws = (char*)d_ws;
    ushort* wt = (ushort*)(ws);                          // 384 KB
    ushort* qb = (ushort*)(ws + (1u << 20));             // 2 MB
    ushort* kb = (ushort*)(ws + (3u << 20));             // 2 MB
    ushort* vt = (ushort*)(ws + (5u << 20));             // 2 MB
    ushort* po = (ushort*)(ws + ((size_t)8 << 20));      // 8 MB partial O (bf16)
    float2* pml = (float2*)(ws + ((size_t)17 << 20));    // 512 KB partial m,l

    prep_w<<<48, 256, 0, stream>>>(Wk, Wq, Wv, wt);
    proj<<<256, 512, 0, stream>>>(x, wt, qb, kb, vt);
    attn<<<512, 512, 0, stream>>>(qb, kb, vt, po, pml);
    merge<<<1024, 256, 0, stream>>>(po, pml, out);
}